// Round 5
// baseline (861.478 us; speedup 1.0000x reference)
//
#include <hip/hip_runtime.h>

#define N_NODES 100000
#define N_EDGES 1600000
#define IN_FEAT 128
#define OUT_FEAT 64
#define LRELU_SLOPE 0.2f
#define EPS_DENOM 1e-16f

#define BKT_SHIFT 7
#define BKT_NODES 128
#define N_BKT ((N_NODES + BKT_NODES - 1) / BKT_NODES)   // 782
#define N_SUB 8
#define SUB_CAP 384                                      // mean 256, ~8 sigma headroom
#define STAGE_CAP (N_SUB * SUB_CAP)                      // 3072
#define CH 4096                                          // edges per scatter block
#define SCAT_BLOCKS ((N_EDGES + CH - 1) / CH)            // 391

// ---- float atomic-max via order-preserving uint encoding ----
__device__ __forceinline__ unsigned int enc_f(float x) {
    unsigned int u = __float_as_uint(x);
    return (u & 0x80000000u) ? ~u : (u | 0x80000000u);
}
__device__ __forceinline__ float dec_f(unsigned int u) {
    u = (u & 0x80000000u) ? (u ^ 0x80000000u) : ~u;
    return __uint_as_float(u);
}
#define ENC_NEG_INF 0x007FFFFFu

// init cursorA; block 0 also computes p = W@a_src, q = W@a_tgt (pq[0:128]=p, pq[128:256]=q)
__global__ __launch_bounds__(256) void init_prep_kernel(
    const float* __restrict__ W, const float* __restrict__ a,
    float* __restrict__ pq, int* __restrict__ cursorA)
{
    const int i = blockIdx.x * 256 + threadIdx.x;
    if (i < N_BKT * N_SUB) cursorA[i] = i * SUB_CAP;
    if (blockIdx.x == 0) {
        const int tid = threadIdx.x;
        const int k = tid & 127;
        const float* av = (tid < 128) ? a : (a + OUT_FEAT);
        float acc = 0.0f;
        #pragma unroll 8
        for (int j = 0; j < OUT_FEAT; ++j) acc += W[k * OUT_FEAT + j] * av[j];
        pq[tid] = acc;
    }
}

// s_src[r] = x[r]·p, s_tgt[r] = x[r]·q.  16 lanes per row, 8 floats per lane.
__global__ __launch_bounds__(256) void score_kernel(
    const float* __restrict__ x, const float* __restrict__ pq,
    float* __restrict__ s_src, float* __restrict__ s_tgt)
{
    __shared__ float spq[256];
    spq[threadIdx.x] = pq[threadIdx.x];
    __syncthreads();
    const int gid = blockIdx.x * 256 + threadIdx.x;
    const int r = gid >> 4, part = gid & 15;
    const float4* xp = (const float4*)(x + (size_t)r * IN_FEAT + part * 8);
    const float4 x0 = xp[0], x1 = xp[1];
    const float* pp = spq + part * 8;
    const float* qq = spq + 128 + part * 8;
    float ss = x0.x*pp[0] + x0.y*pp[1] + x0.z*pp[2] + x0.w*pp[3]
             + x1.x*pp[4] + x1.y*pp[5] + x1.z*pp[6] + x1.w*pp[7];
    float st = x0.x*qq[0] + x0.y*qq[1] + x0.z*qq[2] + x0.w*qq[3]
             + x1.x*qq[4] + x1.y*qq[5] + x1.z*qq[6] + x1.w*qq[7];
    #pragma unroll
    for (int off = 8; off; off >>= 1) {
        ss += __shfl_xor(ss, off, 16);
        st += __shfl_xor(st, off, 16);
    }
    if (part == 0) { s_src[r] = ss; s_tgt[r] = st; }
}

// Wh = x @ W (plain tiled GEMM, no epilogue)
__global__ __launch_bounds__(256) void gemm_kernel(
    const float* __restrict__ x, const float* __restrict__ W,
    float* __restrict__ Wh)
{
    __shared__ __align__(16) float Ws[IN_FEAT * OUT_FEAT];   // 32 KB
    __shared__ __align__(16) float Xs[32 * IN_FEAT];         // 16 KB
    const int tx = threadIdx.x, ty = threadIdx.y;
    const int tid = ty * 64 + tx;
    const int r0 = blockIdx.x * 32;

    for (int i = tid; i < IN_FEAT * OUT_FEAT; i += 256) Ws[i] = W[i];
    for (int i = tid; i < 32 * IN_FEAT; i += 256) Xs[i] = x[r0 * IN_FEAT + i];
    __syncthreads();

    float acc[8];
    #pragma unroll
    for (int rr = 0; rr < 8; ++rr) acc[rr] = 0.0f;

    for (int k = 0; k < IN_FEAT; k += 4) {
        const float w0 = Ws[(k + 0) * OUT_FEAT + tx];
        const float w1 = Ws[(k + 1) * OUT_FEAT + tx];
        const float w2 = Ws[(k + 2) * OUT_FEAT + tx];
        const float w3 = Ws[(k + 3) * OUT_FEAT + tx];
        #pragma unroll
        for (int rr = 0; rr < 8; ++rr) {
            const float4 xv = *(const float4*)&Xs[(ty * 8 + rr) * IN_FEAT + k];
            acc[rr] += xv.x * w0 + xv.y * w1 + xv.z * w2 + xv.w * w3;
        }
    }
    #pragma unroll
    for (int rr = 0; rr < 8; ++rr)
        Wh[(size_t)(r0 + ty * 8 + rr) * OUT_FEAT + tx] = acc[rr];
}

// LDS-binned scatter: 4096 edges/block, one reserve atomic per (block,bucket),
// deposits packed (src | tgt_low<<17, e) into XCD-local sub-regions.
__global__ __launch_bounds__(256) void scatter_kernel(
    const int* __restrict__ ei, const float* __restrict__ s_src,
    const float* __restrict__ s_tgt, int* __restrict__ cursorA,
    int2* __restrict__ bucketsA)
{
    __shared__ int hcnt[N_BKT];
    __shared__ int gbase[N_BKT];
    __shared__ int lcnt[N_BKT];
    const int tid = threadIdx.x;
    const int base = blockIdx.x * CH;
    const int sub = blockIdx.x & (N_SUB - 1);   // ~XCD id under round-robin dispatch

    for (int j = tid; j < N_BKT; j += 256) hcnt[j] = 0;
    __syncthreads();
    #pragma unroll
    for (int k = 0; k < CH / 256; ++k) {
        const int i = base + k * 256 + tid;
        if (i < N_EDGES) atomicAdd(&hcnt[ei[N_EDGES + i] >> BKT_SHIFT], 1);
    }
    __syncthreads();
    for (int j = tid; j < N_BKT; j += 256) {
        lcnt[j] = 0;
        const int c = hcnt[j];
        gbase[j] = c ? atomicAdd(&cursorA[j * N_SUB + sub], c) : 0;
    }
    __syncthreads();
    #pragma unroll
    for (int k = 0; k < CH / 256; ++k) {
        const int i = base + k * 256 + tid;
        if (i < N_EDGES) {
            const int s = ei[i];
            const int t = ei[N_EDGES + i];
            float v = s_src[s] + s_tgt[t];
            v = (v >= 0.0f) ? v : LRELU_SLOPE * v;
            const int bkt = t >> BKT_SHIFT;
            const int r = atomicAdd(&lcnt[bkt], 1);
            bucketsA[gbase[bkt] + r] =
                make_int2(s | ((t & (BKT_NODES - 1)) << 17), __float_as_int(v));
        }
    }
}

// Fused per-bucket: stage edges -> per-node max -> unnormalized weighted
// accumulate into LDS h + sum -> scale + ELU -> coalesced out.
__global__ __launch_bounds__(256) void bucket_aggr_kernel(
    const int* __restrict__ cursorA, const int2* __restrict__ bucketsA,
    const float* __restrict__ Wh, float* __restrict__ out)
{
    __shared__ int2 stage[STAGE_CAP];                 // 24 KB
    __shared__ float h[BKT_NODES * OUT_FEAT];         // 32 KB
    __shared__ unsigned int m_enc[BKT_NODES];
    __shared__ float ssum[BKT_NODES];
    __shared__ int c_ofs[N_SUB + 1];
    const int b = blockIdx.x;
    const int tid = threadIdx.x;

    for (int i = tid; i < BKT_NODES * OUT_FEAT; i += 256) h[i] = 0.0f;
    if (tid < BKT_NODES) { m_enc[tid] = ENC_NEG_INF; ssum[tid] = 0.0f; }
    if (tid == 0) {
        int o = 0;
        #pragma unroll
        for (int s2 = 0; s2 < N_SUB; ++s2) {
            c_ofs[s2] = o;
            o += cursorA[b * N_SUB + s2] - (b * N_SUB + s2) * SUB_CAP;
        }
        c_ofs[N_SUB] = o;
    }
    __syncthreads();
    const int tot = c_ofs[N_SUB];
    #pragma unroll
    for (int s2 = 0; s2 < N_SUB; ++s2) {
        const int o = c_ofs[s2];
        const int c = c_ofs[s2 + 1] - o;
        const int2* src = bucketsA + (size_t)(b * N_SUB + s2) * SUB_CAP;
        for (int k = tid; k < c; k += 256) stage[o + k] = src[k];
    }
    __syncthreads();

    // pass 1: per-node max
    for (int i = tid; i < tot; i += 256) {
        const int2 pk = stage[i];
        atomicMax(&m_enc[(pk.x >> 17) & (BKT_NODES - 1)], enc_f(__int_as_float(pk.y)));
    }
    __syncthreads();

    // pass 2: wave per edge (lane = feature), 4-deep unroll for gather ILP
    const int wv = tid >> 6, lane = tid & 63;
    const int beg = (wv * tot) >> 2;
    const int end = ((wv + 1) * tot) >> 2;
    int i = beg;
    for (; i + 4 <= end; i += 4) {
        const int2 p0 = stage[i], p1 = stage[i + 1], p2 = stage[i + 2], p3 = stage[i + 3];
        const int t0 = (p0.x >> 17) & 127, t1 = (p1.x >> 17) & 127;
        const int t2 = (p2.x >> 17) & 127, t3 = (p3.x >> 17) & 127;
        const float g0 = Wh[(size_t)(p0.x & 0x1FFFF) * OUT_FEAT + lane];
        const float g1 = Wh[(size_t)(p1.x & 0x1FFFF) * OUT_FEAT + lane];
        const float g2 = Wh[(size_t)(p2.x & 0x1FFFF) * OUT_FEAT + lane];
        const float g3 = Wh[(size_t)(p3.x & 0x1FFFF) * OUT_FEAT + lane];
        const float w0 = expf(__int_as_float(p0.y) - dec_f(m_enc[t0]));
        const float w1 = expf(__int_as_float(p1.y) - dec_f(m_enc[t1]));
        const float w2 = expf(__int_as_float(p2.y) - dec_f(m_enc[t2]));
        const float w3 = expf(__int_as_float(p3.y) - dec_f(m_enc[t3]));
        atomicAdd(&h[t0 * OUT_FEAT + lane], w0 * g0);
        atomicAdd(&h[t1 * OUT_FEAT + lane], w1 * g1);
        atomicAdd(&h[t2 * OUT_FEAT + lane], w2 * g2);
        atomicAdd(&h[t3 * OUT_FEAT + lane], w3 * g3);
        if (lane == 0) {
            atomicAdd(&ssum[t0], w0); atomicAdd(&ssum[t1], w1);
            atomicAdd(&ssum[t2], w2); atomicAdd(&ssum[t3], w3);
        }
    }
    for (; i < end; ++i) {
        const int2 pk = stage[i];
        const int tl = (pk.x >> 17) & 127;
        const float g = Wh[(size_t)(pk.x & 0x1FFFF) * OUT_FEAT + lane];
        const float w = expf(__int_as_float(pk.y) - dec_f(m_enc[tl]));
        atomicAdd(&h[tl * OUT_FEAT + lane], w * g);
        if (lane == 0) atomicAdd(&ssum[tl], w);
    }
    __syncthreads();

    // out = elu(h / (sum + eps)), coalesced
    for (int r = wv; r < BKT_NODES; r += 4) {
        const int node = b * BKT_NODES + r;
        if (node < N_NODES) {
            const float inv = 1.0f / (ssum[r] + EPS_DENOM);
            const float val = h[r * OUT_FEAT + lane] * inv;
            out[(size_t)node * OUT_FEAT + lane] = (val > 0.0f) ? val : expm1f(val);
        }
    }
}

extern "C" void kernel_launch(void* const* d_in, const int* in_sizes, int n_in,
                              void* d_out, int out_size, void* d_ws, size_t ws_size,
                              hipStream_t stream) {
    const float* x  = (const float*)d_in[0];
    const int*   ei = (const int*)d_in[1];     // int64 in reference -> int32 on device
    const float* W  = (const float*)d_in[2];
    const float* a  = (const float*)d_in[3];
    float* out = (float*)d_out;

    // workspace (~46 MB)
    char* p = (char*)d_ws;
    float* Wh       = (float*)p;  p += (size_t)N_NODES * OUT_FEAT * 4;           // 25.6 MB
    float* s_src    = (float*)p;  p += (size_t)N_NODES * 4;
    float* s_tgt    = (float*)p;  p += (size_t)N_NODES * 4;
    float* pq       = (float*)p;  p += 256 * 4;
    int*   cursorA  = (int*)p;    p += (size_t)N_BKT * N_SUB * 4;
    p = (char*)(((size_t)p + 15) & ~(size_t)15);
    int2*  bucketsA = (int2*)p;   p += (size_t)N_BKT * N_SUB * SUB_CAP * 8;      // 19.2 MB

    init_prep_kernel<<<(N_BKT * N_SUB + 255) / 256, 256, 0, stream>>>(W, a, pq, cursorA);
    score_kernel<<<(N_NODES * 16) / 256, 256, 0, stream>>>(x, pq, s_src, s_tgt);
    gemm_kernel<<<N_NODES / 32, dim3(64, 4), 0, stream>>>(x, W, Wh);
    scatter_kernel<<<SCAT_BLOCKS, 256, 0, stream>>>(ei, s_src, s_tgt, cursorA, bucketsA);
    bucket_aggr_kernel<<<N_BKT, 256, 0, stream>>>(cursorA, bucketsA, Wh, out);
}

// Round 6
// 207.572 us; speedup vs baseline: 4.1503x; 4.1503x over previous
//
#include <hip/hip_runtime.h>

#define N_NODES 100000
#define N_EDGES 1600000
#define IN_FEAT 128
#define OUT_FEAT 64
#define LRELU_SLOPE 0.2f
#define EPS_DENOM 1e-16f

#define BKT_SHIFT 7
#define BKT_NODES 128
#define N_BKT ((N_NODES + BKT_NODES - 1) / BKT_NODES)   // 782
#define N_SUB 8
#define SUB_CAP 384                                      // mean 256/sub, ~8 sigma headroom
#define STAGE_CAP (N_SUB * SUB_CAP)                      // 3072 (mean 2048/bucket)
#define CH 4096                                          // edges per scatter block
#define SCAT_BLOCKS ((N_EDGES + CH - 1) / CH)            // 391

__global__ __launch_bounds__(256) void init_kernel(int* __restrict__ cursorA) {
    const int i = blockIdx.x * 256 + threadIdx.x;
    if (i < N_BKT * N_SUB) cursorA[i] = i * SUB_CAP;     // static sub-region starts
}

// Wh(bf16) = x @ W, fused s_src/s_tgt epilogue via wave reduce.
// Block 64x4; each block: 32 rows; each thread: 8 rows x 1 col.
__global__ __launch_bounds__(256) void gemm_score_kernel(
    const float* __restrict__ x, const float* __restrict__ W,
    const float* __restrict__ a, unsigned short* __restrict__ WhB,
    float* __restrict__ s_src, float* __restrict__ s_tgt)
{
    __shared__ __align__(16) float Ws[IN_FEAT * OUT_FEAT];   // 32 KB
    __shared__ __align__(16) float Xs[32 * IN_FEAT];         // 16 KB
    const int tx = threadIdx.x, ty = threadIdx.y;
    const int tid = ty * 64 + tx;
    const int r0 = blockIdx.x * 32;

    for (int i = tid; i < IN_FEAT * OUT_FEAT; i += 256) Ws[i] = W[i];
    for (int i = tid; i < 32 * IN_FEAT; i += 256) Xs[i] = x[r0 * IN_FEAT + i];
    __syncthreads();

    float acc[8];
    #pragma unroll
    for (int rr = 0; rr < 8; ++rr) acc[rr] = 0.0f;

    for (int k = 0; k < IN_FEAT; k += 4) {
        const float w0 = Ws[(k + 0) * OUT_FEAT + tx];
        const float w1 = Ws[(k + 1) * OUT_FEAT + tx];
        const float w2 = Ws[(k + 2) * OUT_FEAT + tx];
        const float w3 = Ws[(k + 3) * OUT_FEAT + tx];
        #pragma unroll
        for (int rr = 0; rr < 8; ++rr) {
            const float4 xv = *(const float4*)&Xs[(ty * 8 + rr) * IN_FEAT + k];
            acc[rr] += xv.x * w0 + xv.y * w1 + xv.z * w2 + xv.w * w3;
        }
    }

    const float a_s = a[tx];
    const float a_t = a[OUT_FEAT + tx];
    #pragma unroll
    for (int rr = 0; rr < 8; ++rr) {
        const int row = r0 + ty * 8 + rr;
        // bf16 round-to-nearest-even
        unsigned int u = __float_as_uint(acc[rr]);
        u = (u + 0x7FFFu + ((u >> 16) & 1u)) >> 16;
        WhB[(size_t)row * OUT_FEAT + tx] = (unsigned short)u;
        float ss = acc[rr] * a_s;
        float st = acc[rr] * a_t;
        #pragma unroll
        for (int off = 32; off; off >>= 1) {
            ss += __shfl_xor(ss, off, 64);
            st += __shfl_xor(st, off, 64);
        }
        if (tx == 0) { s_src[row] = ss; s_tgt[row] = st; }
    }
}

// LDS-binned scatter: 4096 edges/block, one reserve atomic per (block,bucket),
// deposits packed (src | tgt_low<<17, e) into XCD-local sub-regions.  [proven ~45us]
__global__ __launch_bounds__(256) void scatter_kernel(
    const int* __restrict__ ei, const float* __restrict__ s_src,
    const float* __restrict__ s_tgt, int* __restrict__ cursorA,
    int2* __restrict__ bucketsA)
{
    __shared__ int hcnt[N_BKT];
    __shared__ int gbase[N_BKT];
    __shared__ int lcnt[N_BKT];
    const int tid = threadIdx.x;
    const int base = blockIdx.x * CH;
    const int sub = blockIdx.x & (N_SUB - 1);   // ~XCD id under round-robin dispatch

    for (int j = tid; j < N_BKT; j += 256) hcnt[j] = 0;
    __syncthreads();
    #pragma unroll
    for (int k = 0; k < CH / 256; ++k) {
        const int i = base + k * 256 + tid;
        if (i < N_EDGES) atomicAdd(&hcnt[ei[N_EDGES + i] >> BKT_SHIFT], 1);
    }
    __syncthreads();
    for (int j = tid; j < N_BKT; j += 256) {
        lcnt[j] = 0;
        const int c = hcnt[j];
        gbase[j] = c ? atomicAdd(&cursorA[j * N_SUB + sub], c) : 0;
    }
    __syncthreads();
    #pragma unroll
    for (int k = 0; k < CH / 256; ++k) {
        const int i = base + k * 256 + tid;
        if (i < N_EDGES) {
            const int s = ei[i];
            const int t = ei[N_EDGES + i];
            float v = s_src[s] + s_tgt[t];
            v = (v >= 0.0f) ? v : LRELU_SLOPE * v;
            const int bkt = t >> BKT_SHIFT;
            const int r = atomicAdd(&lcnt[bkt], 1);
            bucketsA[gbase[bkt] + r] =
                make_int2(s | ((t & (BKT_NODES - 1)) << 17), __float_as_int(v));
        }
    }
}

// One block per bucket: stage edges in LDS, per-node count + LDS scan,
// deposit into padded per-bucket region of sorted_se (base b*STAGE_CAP),
// emit packed seg[node] = beg<<10 | cnt.  No global scan needed.
__global__ __launch_bounds__(256) void sort_bucket_kernel(
    const int* __restrict__ cursorA, const int2* __restrict__ bucketsA,
    int2* __restrict__ sorted_se, unsigned int* __restrict__ segA)
{
    __shared__ int2 stage[STAGE_CAP];     // 24 KB
    __shared__ int cnt[BKT_NODES];
    __shared__ int pfx[BKT_NODES];
    __shared__ int cur[BKT_NODES];
    __shared__ int c_ofs[N_SUB + 1];
    const int b = blockIdx.x;
    const int tid = threadIdx.x;

    if (tid < BKT_NODES) cnt[tid] = 0;
    if (tid == 0) {
        int o = 0;
        #pragma unroll
        for (int s = 0; s < N_SUB; ++s) {
            c_ofs[s] = o;
            o += cursorA[b * N_SUB + s] - (b * N_SUB + s) * SUB_CAP;
        }
        c_ofs[N_SUB] = o;
    }
    __syncthreads();
    const int tot = c_ofs[N_SUB];
    #pragma unroll
    for (int s = 0; s < N_SUB; ++s) {
        const int o = c_ofs[s];
        const int c = c_ofs[s + 1] - o;
        const int2* src = bucketsA + (size_t)(b * N_SUB + s) * SUB_CAP;
        for (int k = tid; k < c; k += 256) stage[o + k] = src[k];
    }
    __syncthreads();
    for (int i = tid; i < tot; i += 256)
        atomicAdd(&cnt[(stage[i].x >> 17) & (BKT_NODES - 1)], 1);
    __syncthreads();
    // inclusive scan over 128 counts (Hillis-Steele)
    if (tid < BKT_NODES) pfx[tid] = cnt[tid];
    __syncthreads();
    for (int off = 1; off < BKT_NODES; off <<= 1) {
        int add = (tid < BKT_NODES && tid >= off) ? pfx[tid - off] : 0;
        __syncthreads();
        if (tid < BKT_NODES) pfx[tid] += add;
        __syncthreads();
    }
    if (tid < BKT_NODES) {
        const int ex = pfx[tid] - cnt[tid];    // exclusive
        cur[tid] = ex;
        const int node = b * BKT_NODES + tid;
        if (node < N_NODES)
            segA[node] = ((unsigned int)(b * STAGE_CAP + ex) << 10) | (unsigned int)cnt[tid];
    }
    __syncthreads();
    for (int i = tid; i < tot; i += 256) {
        const int2 pk = stage[i];
        const int tl = (pk.x >> 17) & (BKT_NODES - 1);
        const int pos = atomicAdd(&cur[tl], 1);
        sorted_se[(size_t)b * STAGE_CAP + pos] = make_int2(pk.x & 0x1FFFF, pk.y);
    }
}

// Fused per-node softmax + weighted gather of bf16 Wh rows + ELU.
// One wave per node; lane = output feature.  [86% occupancy structure, round 3]
__global__ __launch_bounds__(256) void node_aggr_kernel(
    const unsigned int* __restrict__ segA, const int2* __restrict__ sorted_se,
    const unsigned short* __restrict__ WhB, float* __restrict__ out)
{
    const int wid = (blockIdx.x * 256 + threadIdx.x) >> 6;   // node id
    const int lane = threadIdx.x & 63;
    if (wid >= N_NODES) return;
    const unsigned int sg = segA[wid];
    const int beg = (int)(sg >> 10);
    const int end = beg + (int)(sg & 1023u);

    // pass 1: segment max
    float m = -__builtin_inff();
    for (int i = beg + lane; i < end; i += 64)
        m = fmaxf(m, __int_as_float(sorted_se[i].y));
    #pragma unroll
    for (int off = 32; off; off >>= 1) m = fmaxf(m, __shfl_xor(m, off, 64));

    // pass 2: segment sum of exp
    float sum = 0.0f;
    for (int i = beg + lane; i < end; i += 64)
        sum += expf(__int_as_float(sorted_se[i].y) - m);
    #pragma unroll
    for (int off = 32; off; off >>= 1) sum += __shfl_xor(sum, off, 64);
    const float inv = 1.0f / (sum + EPS_DENOM);

    // pass 3: acc[f] = sum_e exp(e-m) * Wh[src_e][f]   (lane = f; 4 edges in flight)
    float acc = 0.0f;
    int i = beg;
    for (; i + 4 <= end; i += 4) {
        const int2 p0 = sorted_se[i],     p1 = sorted_se[i + 1];
        const int2 p2 = sorted_se[i + 2], p3 = sorted_se[i + 3];
        const float g0 = __uint_as_float((unsigned int)WhB[(size_t)p0.x * OUT_FEAT + lane] << 16);
        const float g1 = __uint_as_float((unsigned int)WhB[(size_t)p1.x * OUT_FEAT + lane] << 16);
        const float g2 = __uint_as_float((unsigned int)WhB[(size_t)p2.x * OUT_FEAT + lane] << 16);
        const float g3 = __uint_as_float((unsigned int)WhB[(size_t)p3.x * OUT_FEAT + lane] << 16);
        acc += expf(__int_as_float(p0.y) - m) * g0;
        acc += expf(__int_as_float(p1.y) - m) * g1;
        acc += expf(__int_as_float(p2.y) - m) * g2;
        acc += expf(__int_as_float(p3.y) - m) * g3;
    }
    for (; i < end; ++i) {
        const int2 pk = sorted_se[i];
        const float g = __uint_as_float((unsigned int)WhB[(size_t)pk.x * OUT_FEAT + lane] << 16);
        acc += expf(__int_as_float(pk.y) - m) * g;
    }

    const float val = acc * inv;
    out[(size_t)wid * OUT_FEAT + lane] = (val > 0.0f) ? val : expm1f(val);
}

extern "C" void kernel_launch(void* const* d_in, const int* in_sizes, int n_in,
                              void* d_out, int out_size, void* d_ws, size_t ws_size,
                              hipStream_t stream) {
    const float* x  = (const float*)d_in[0];
    const int*   ei = (const int*)d_in[1];     // int64 in reference -> int32 on device
    const float* W  = (const float*)d_in[2];
    const float* a  = (const float*)d_in[3];
    float* out = (float*)d_out;

    // workspace (~53 MB)
    char* p = (char*)d_ws;
    unsigned short* WhB = (unsigned short*)p; p += (size_t)N_NODES * OUT_FEAT * 2; // 12.8 MB
    float* s_src    = (float*)p;  p += (size_t)N_NODES * 4;
    float* s_tgt    = (float*)p;  p += (size_t)N_NODES * 4;
    unsigned int* segA = (unsigned int*)p; p += (size_t)N_NODES * 4;
    int*   cursorA  = (int*)p;    p += (size_t)N_BKT * N_SUB * 4;
    p = (char*)(((size_t)p + 15) & ~(size_t)15);
    int2*  bucketsA = (int2*)p;   p += (size_t)N_BKT * N_SUB * SUB_CAP * 8;        // 19.2 MB
    int2*  sorted_se = (int2*)p;  p += (size_t)N_BKT * STAGE_CAP * 8;              // 19.2 MB

    init_kernel<<<(N_BKT * N_SUB + 255) / 256, 256, 0, stream>>>(cursorA);
    gemm_score_kernel<<<N_NODES / 32, dim3(64, 4), 0, stream>>>(x, W, a, WhB, s_src, s_tgt);
    scatter_kernel<<<SCAT_BLOCKS, 256, 0, stream>>>(ei, s_src, s_tgt, cursorA, bucketsA);
    sort_bucket_kernel<<<N_BKT, 256, 0, stream>>>(cursorA, bucketsA, sorted_se, segA);
    node_aggr_kernel<<<(N_NODES * 64 + 255) / 256, 256, 0, stream>>>(segA, sorted_se, WhB, out);
}

// Round 7
// 188.784 us; speedup vs baseline: 4.5633x; 1.0995x over previous
//
#include <hip/hip_runtime.h>

#define N_NODES 100000
#define N_EDGES 1600000
#define IN_FEAT 128
#define OUT_FEAT 64
#define LRELU_SLOPE 0.2f
#define EPS_DENOM 1e-16f

#define BKT_SHIFT 7
#define BKT_NODES 128
#define N_BKT ((N_NODES + BKT_NODES - 1) / BKT_NODES)   // 782
#define N_SUB 8
#define SUB_CAP 384                                      // mean 256/sub, ~8 sigma headroom
#define STAGE_CAP (N_SUB * SUB_CAP)                      // 3072 (mean 2048/bucket)
#define CH 4096                                          // edges per scatter block
#define SCAT_BLOCKS ((N_EDGES + CH - 1) / CH)            // 391

// ---- float atomic-max via order-preserving uint encoding ----
__device__ __forceinline__ unsigned int enc_f(float x) {
    unsigned int u = __float_as_uint(x);
    return (u & 0x80000000u) ? ~u : (u | 0x80000000u);
}
__device__ __forceinline__ float dec_f(unsigned int u) {
    u = (u & 0x80000000u) ? (u ^ 0x80000000u) : ~u;
    return __uint_as_float(u);
}
#define ENC_NEG_INF 0x007FFFFFu

__global__ __launch_bounds__(256) void init_kernel(int* __restrict__ cursorA) {
    const int i = blockIdx.x * 256 + threadIdx.x;
    if (i < N_BKT * N_SUB) cursorA[i] = i * SUB_CAP;     // static sub-region starts
}

// Wh(bf16) = x @ W, fused s_src/s_tgt epilogue via wave reduce.
// Block 64x4; each block: 32 rows; each thread: 8 rows x 1 col.
__global__ __launch_bounds__(256) void gemm_score_kernel(
    const float* __restrict__ x, const float* __restrict__ W,
    const float* __restrict__ a, unsigned short* __restrict__ WhB,
    float* __restrict__ s_src, float* __restrict__ s_tgt)
{
    __shared__ __align__(16) float Ws[IN_FEAT * OUT_FEAT];   // 32 KB
    __shared__ __align__(16) float Xs[32 * IN_FEAT];         // 16 KB
    const int tx = threadIdx.x, ty = threadIdx.y;
    const int tid = ty * 64 + tx;
    const int r0 = blockIdx.x * 32;

    {   // vectorized staging
        const float4* W4 = (const float4*)W;
        float4* Ws4 = (float4*)Ws;
        for (int i = tid; i < IN_FEAT * OUT_FEAT / 4; i += 256) Ws4[i] = W4[i];
        const float4* x4 = (const float4*)(x + (size_t)r0 * IN_FEAT);
        float4* Xs4 = (float4*)Xs;
        for (int i = tid; i < 32 * IN_FEAT / 4; i += 256) Xs4[i] = x4[i];
    }
    __syncthreads();

    float acc[8];
    #pragma unroll
    for (int rr = 0; rr < 8; ++rr) acc[rr] = 0.0f;

    for (int k = 0; k < IN_FEAT; k += 4) {
        const float w0 = Ws[(k + 0) * OUT_FEAT + tx];
        const float w1 = Ws[(k + 1) * OUT_FEAT + tx];
        const float w2 = Ws[(k + 2) * OUT_FEAT + tx];
        const float w3 = Ws[(k + 3) * OUT_FEAT + tx];
        #pragma unroll
        for (int rr = 0; rr < 8; ++rr) {
            const float4 xv = *(const float4*)&Xs[(ty * 8 + rr) * IN_FEAT + k];
            acc[rr] += xv.x * w0 + xv.y * w1 + xv.z * w2 + xv.w * w3;
        }
    }

    const float a_s = a[tx];
    const float a_t = a[OUT_FEAT + tx];
    #pragma unroll
    for (int rr = 0; rr < 8; ++rr) {
        const int row = r0 + ty * 8 + rr;
        // bf16 round-to-nearest-even
        unsigned int u = __float_as_uint(acc[rr]);
        u = (u + 0x7FFFu + ((u >> 16) & 1u)) >> 16;
        WhB[(size_t)row * OUT_FEAT + tx] = (unsigned short)u;
        float ss = acc[rr] * a_s;
        float st = acc[rr] * a_t;
        #pragma unroll
        for (int off = 32; off; off >>= 1) {
            ss += __shfl_xor(ss, off, 64);
            st += __shfl_xor(st, off, 64);
        }
        if (tx == 0) { s_src[row] = ss; s_tgt[row] = st; }
    }
}

// LDS-binned scatter: 4096 edges/block, one reserve atomic per (block,bucket),
// deposits packed (src | tgt_low<<17, e) into XCD-local sub-regions.  [proven]
__global__ __launch_bounds__(256) void scatter_kernel(
    const int* __restrict__ ei, const float* __restrict__ s_src,
    const float* __restrict__ s_tgt, int* __restrict__ cursorA,
    int2* __restrict__ bucketsA)
{
    __shared__ int hcnt[N_BKT];
    __shared__ int gbase[N_BKT];
    __shared__ int lcnt[N_BKT];
    const int tid = threadIdx.x;
    const int base = blockIdx.x * CH;
    const int sub = blockIdx.x & (N_SUB - 1);   // ~XCD id under round-robin dispatch

    for (int j = tid; j < N_BKT; j += 256) hcnt[j] = 0;
    __syncthreads();
    #pragma unroll
    for (int k = 0; k < CH / 256; ++k) {
        const int i = base + k * 256 + tid;
        if (i < N_EDGES) atomicAdd(&hcnt[ei[N_EDGES + i] >> BKT_SHIFT], 1);
    }
    __syncthreads();
    for (int j = tid; j < N_BKT; j += 256) {
        lcnt[j] = 0;
        const int c = hcnt[j];
        gbase[j] = c ? atomicAdd(&cursorA[j * N_SUB + sub], c) : 0;
    }
    __syncthreads();
    #pragma unroll
    for (int k = 0; k < CH / 256; ++k) {
        const int i = base + k * 256 + tid;
        if (i < N_EDGES) {
            const int s = ei[i];
            const int t = ei[N_EDGES + i];
            float v = s_src[s] + s_tgt[t];
            v = (v >= 0.0f) ? v : LRELU_SLOPE * v;
            const int bkt = t >> BKT_SHIFT;
            const int r = atomicAdd(&lcnt[bkt], 1);
            bucketsA[gbase[bkt] + r] =
                make_int2(s | ((t & (BKT_NODES - 1)) << 17), __float_as_int(v));
        }
    }
}

// One block per bucket: stage edges in LDS, per-node count+max, LDS scan,
// deposit (src, w=exp(v-m)) into padded per-bucket region of sorted_se,
// emit packed seg[node] = beg<<10 | cnt.  No global scan, no exp downstream.
__global__ __launch_bounds__(256) void sort_bucket_kernel(
    const int* __restrict__ cursorA, const int2* __restrict__ bucketsA,
    int2* __restrict__ sorted_se, unsigned int* __restrict__ segA)
{
    __shared__ int2 stage[STAGE_CAP];     // 24 KB
    __shared__ int cnt[BKT_NODES];
    __shared__ int pfx[BKT_NODES];
    __shared__ int cur[BKT_NODES];
    __shared__ unsigned int m_enc[BKT_NODES];
    __shared__ int c_ofs[N_SUB + 1];
    const int b = blockIdx.x;
    const int tid = threadIdx.x;

    if (tid < BKT_NODES) { cnt[tid] = 0; m_enc[tid] = ENC_NEG_INF; }
    if (tid == 0) {
        int o = 0;
        #pragma unroll
        for (int s = 0; s < N_SUB; ++s) {
            c_ofs[s] = o;
            o += cursorA[b * N_SUB + s] - (b * N_SUB + s) * SUB_CAP;
        }
        c_ofs[N_SUB] = o;
    }
    __syncthreads();
    const int tot = c_ofs[N_SUB];
    #pragma unroll
    for (int s = 0; s < N_SUB; ++s) {
        const int o = c_ofs[s];
        const int c = c_ofs[s + 1] - o;
        const int2* src = bucketsA + (size_t)(b * N_SUB + s) * SUB_CAP;
        for (int k = tid; k < c; k += 256) stage[o + k] = src[k];
    }
    __syncthreads();
    for (int i = tid; i < tot; i += 256) {
        const int2 pk = stage[i];
        const int tl = (pk.x >> 17) & (BKT_NODES - 1);
        atomicAdd(&cnt[tl], 1);
        atomicMax(&m_enc[tl], enc_f(__int_as_float(pk.y)));
    }
    __syncthreads();
    // inclusive scan over 128 counts (Hillis-Steele)
    if (tid < BKT_NODES) pfx[tid] = cnt[tid];
    __syncthreads();
    for (int off = 1; off < BKT_NODES; off <<= 1) {
        int add = (tid < BKT_NODES && tid >= off) ? pfx[tid - off] : 0;
        __syncthreads();
        if (tid < BKT_NODES) pfx[tid] += add;
        __syncthreads();
    }
    if (tid < BKT_NODES) {
        const int ex = pfx[tid] - cnt[tid];    // exclusive
        cur[tid] = ex;
        const int node = b * BKT_NODES + tid;
        if (node < N_NODES)
            segA[node] = ((unsigned int)(b * STAGE_CAP + ex) << 10) | (unsigned int)cnt[tid];
    }
    __syncthreads();
    for (int i = tid; i < tot; i += 256) {
        const int2 pk = stage[i];
        const int tl = (pk.x >> 17) & (BKT_NODES - 1);
        const int pos = atomicAdd(&cur[tl], 1);
        const float w = __expf(__int_as_float(pk.y) - dec_f(m_enc[tl]));
        sorted_se[(size_t)b * STAGE_CAP + pos] = make_int2(pk.x & 0x1FFFF, __float_as_int(w));
    }
}

// Single-pass: acc[f] = sum_e w_e * Wh[src_e][f], sum = sum_e w_e (wave-uniform),
// out = elu(acc/(sum+eps)).  One wave per node; lane = feature.
__global__ __launch_bounds__(256) void node_aggr_kernel(
    const unsigned int* __restrict__ segA, const int2* __restrict__ sorted_se,
    const unsigned short* __restrict__ WhB, float* __restrict__ out)
{
    const int wid = (blockIdx.x * 256 + threadIdx.x) >> 6;   // node id
    const int lane = threadIdx.x & 63;
    if (wid >= N_NODES) return;
    const unsigned int sg = segA[wid];
    const int beg = (int)(sg >> 10);
    const int end = beg + (int)(sg & 1023u);

    float acc = 0.0f, sum = 0.0f;
    int i = beg;
    for (; i + 4 <= end; i += 4) {
        const int2 p0 = sorted_se[i],     p1 = sorted_se[i + 1];
        const int2 p2 = sorted_se[i + 2], p3 = sorted_se[i + 3];
        const float g0 = __uint_as_float((unsigned int)WhB[(size_t)p0.x * OUT_FEAT + lane] << 16);
        const float g1 = __uint_as_float((unsigned int)WhB[(size_t)p1.x * OUT_FEAT + lane] << 16);
        const float g2 = __uint_as_float((unsigned int)WhB[(size_t)p2.x * OUT_FEAT + lane] << 16);
        const float g3 = __uint_as_float((unsigned int)WhB[(size_t)p3.x * OUT_FEAT + lane] << 16);
        const float w0 = __int_as_float(p0.y), w1 = __int_as_float(p1.y);
        const float w2 = __int_as_float(p2.y), w3 = __int_as_float(p3.y);
        acc += w0 * g0 + w1 * g1 + w2 * g2 + w3 * g3;
        sum += (w0 + w1) + (w2 + w3);
    }
    for (; i < end; ++i) {
        const int2 pk = sorted_se[i];
        const float w = __int_as_float(pk.y);
        const float g = __uint_as_float((unsigned int)WhB[(size_t)pk.x * OUT_FEAT + lane] << 16);
        acc += w * g;
        sum += w;
    }

    const float val = acc / (sum + EPS_DENOM);
    out[(size_t)wid * OUT_FEAT + lane] = (val > 0.0f) ? val : expm1f(val);
}

extern "C" void kernel_launch(void* const* d_in, const int* in_sizes, int n_in,
                              void* d_out, int out_size, void* d_ws, size_t ws_size,
                              hipStream_t stream) {
    const float* x  = (const float*)d_in[0];
    const int*   ei = (const int*)d_in[1];     // int64 in reference -> int32 on device
    const float* W  = (const float*)d_in[2];
    const float* a  = (const float*)d_in[3];
    float* out = (float*)d_out;

    // workspace (~53 MB)
    char* p = (char*)d_ws;
    unsigned short* WhB = (unsigned short*)p; p += (size_t)N_NODES * OUT_FEAT * 2; // 12.8 MB
    float* s_src    = (float*)p;  p += (size_t)N_NODES * 4;
    float* s_tgt    = (float*)p;  p += (size_t)N_NODES * 4;
    unsigned int* segA = (unsigned int*)p; p += (size_t)N_NODES * 4;
    int*   cursorA  = (int*)p;    p += (size_t)N_BKT * N_SUB * 4;
    p = (char*)(((size_t)p + 15) & ~(size_t)15);
    int2*  bucketsA = (int2*)p;   p += (size_t)N_BKT * N_SUB * SUB_CAP * 8;        // 19.2 MB
    int2*  sorted_se = (int2*)p;  p += (size_t)N_BKT * STAGE_CAP * 8;              // 19.2 MB

    init_kernel<<<(N_BKT * N_SUB + 255) / 256, 256, 0, stream>>>(cursorA);
    gemm_score_kernel<<<N_NODES / 32, dim3(64, 4), 0, stream>>>(x, W, a, WhB, s_src, s_tgt);
    scatter_kernel<<<SCAT_BLOCKS, 256, 0, stream>>>(ei, s_src, s_tgt, cursorA, bucketsA);
    sort_bucket_kernel<<<N_BKT, 256, 0, stream>>>(cursorA, bucketsA, sorted_se, segA);
    node_aggr_kernel<<<(N_NODES * 64 + 255) / 256, 256, 0, stream>>>(segA, sorted_se, WhB, out);
}

// Round 8
// 154.845 us; speedup vs baseline: 5.5635x; 1.2192x over previous
//
#include <hip/hip_runtime.h>

#define N_NODES 100000
#define N_EDGES 1600000
#define IN_FEAT 128
#define OUT_FEAT 64
#define LRELU_SLOPE 0.2f
#define EPS_DENOM 1e-16f

#define BKT_SHIFT 7
#define BKT_NODES 128
#define N_BKT ((N_NODES + BKT_NODES - 1) / BKT_NODES)   // 782
#define N_SUB 8
#define SUB_CAP 384                                      // mean 256/sub, ~8 sigma headroom
#define STAGE_CAP (N_SUB * SUB_CAP)                      // 3072 (mean 2048/bucket)
#define CH 4096                                          // edges per scatter block
#define SCAT_BLOCKS ((N_EDGES + CH - 1) / CH)            // 391

typedef __attribute__((ext_vector_type(8))) short bf16x8;
typedef __attribute__((ext_vector_type(4))) float f32x4;

// ---- float atomic-max via order-preserving uint encoding ----
__device__ __forceinline__ unsigned int enc_f(float x) {
    unsigned int u = __float_as_uint(x);
    return (u & 0x80000000u) ? ~u : (u | 0x80000000u);
}
__device__ __forceinline__ float dec_f(unsigned int u) {
    u = (u & 0x80000000u) ? (u ^ 0x80000000u) : ~u;
    return __uint_as_float(u);
}
#define ENC_NEG_INF 0x007FFFFFu

__device__ __forceinline__ unsigned short f2bf(float f) {   // RNE
    unsigned int u = __float_as_uint(f);
    u = (u + 0x7FFFu + ((u >> 16) & 1u)) >> 16;
    return (unsigned short)u;
}

// init cursorA + convert W -> bf16 transposed WT[n][k]
__global__ __launch_bounds__(256) void init_prep_kernel(
    const float* __restrict__ W, int* __restrict__ cursorA,
    unsigned short* __restrict__ WTb)
{
    const int i = blockIdx.x * 256 + threadIdx.x;
    if (i < N_BKT * N_SUB) cursorA[i] = i * SUB_CAP;     // static sub-region starts
    if (i < OUT_FEAT * IN_FEAT) {
        const int n = i >> 7, k = i & 127;
        WTb[i] = f2bf(W[k * OUT_FEAT + n]);
    }
}

// MFMA GEMM: Wh(bf16) = x @ W, fused s_src/s_tgt epilogue (fp32 acc).
// Block = 64 rows x 64 cols, 4 waves; wave w: 16-col strip, 4 M-tiles.
__global__ __launch_bounds__(256) void gemm_mfma_kernel(
    const float* __restrict__ x, const unsigned short* __restrict__ WTb,
    const float* __restrict__ a, unsigned short* __restrict__ WhB,
    float* __restrict__ s_src, float* __restrict__ s_tgt)
{
    __shared__ __align__(16) unsigned short xs[64][136];   // +8 pad: bank spread
    __shared__ float ssp[4][64], stp[4][64];
    const int tid = threadIdx.x;
    const int wid = tid >> 6, lane = tid & 63;
    const int r0 = blockIdx.x * 64;

    // stage 64x128 fp32 -> bf16 LDS (8 float4 per thread)
    #pragma unroll
    for (int it = 0; it < 8; ++it) {
        const int idx4 = it * 256 + tid;       // float4 index 0..2047
        const int row = idx4 >> 5;             // 32 float4 per row
        const int col = (idx4 & 31) * 4;
        float4 v = make_float4(0.f, 0.f, 0.f, 0.f);
        if (r0 + row < N_NODES) v = *(const float4*)(x + (size_t)(r0 + row) * IN_FEAT + col);
        const unsigned int p0 = (unsigned int)f2bf(v.x) | ((unsigned int)f2bf(v.y) << 16);
        const unsigned int p1 = (unsigned int)f2bf(v.z) | ((unsigned int)f2bf(v.w) << 16);
        *(uint2*)&xs[row][col] = make_uint2(p0, p1);
    }
    __syncthreads();

    const int cgrp = lane >> 4;          // k-subgroup 0..3
    const int cl = lane & 15;
    const int col = wid * 16 + cl;       // output col (N dim)
    f32x4 acc0 = {0.f,0.f,0.f,0.f}, acc1 = acc0, acc2 = acc0, acc3 = acc0;
    #pragma unroll
    for (int kb = 0; kb < IN_FEAT; kb += 32) {
        const bf16x8 bfrag = *(const bf16x8*)(WTb + col * IN_FEAT + kb + cgrp * 8);
        const bf16x8 a0 = *(const bf16x8*)&xs[ 0 + cl][kb + cgrp * 8];
        const bf16x8 a1 = *(const bf16x8*)&xs[16 + cl][kb + cgrp * 8];
        const bf16x8 a2 = *(const bf16x8*)&xs[32 + cl][kb + cgrp * 8];
        const bf16x8 a3 = *(const bf16x8*)&xs[48 + cl][kb + cgrp * 8];
        acc0 = __builtin_amdgcn_mfma_f32_16x16x32_bf16(a0, bfrag, acc0, 0, 0, 0);
        acc1 = __builtin_amdgcn_mfma_f32_16x16x32_bf16(a1, bfrag, acc1, 0, 0, 0);
        acc2 = __builtin_amdgcn_mfma_f32_16x16x32_bf16(a2, bfrag, acc2, 0, 0, 0);
        acc3 = __builtin_amdgcn_mfma_f32_16x16x32_bf16(a3, bfrag, acc3, 0, 0, 0);
    }

    // epilogue: C/D layout col=lane&15, row=(lane>>4)*4+reg
    const float a_s = a[col], a_t = a[OUT_FEAT + col];
    #pragma unroll
    for (int mt = 0; mt < 4; ++mt) {
        const f32x4 av = (mt == 0) ? acc0 : (mt == 1) ? acc1 : (mt == 2) ? acc2 : acc3;
        #pragma unroll
        for (int r = 0; r < 4; ++r) {
            const int lrow = mt * 16 + cgrp * 4 + r;
            const float v = av[r];
            const int grow = r0 + lrow;
            if (grow < N_NODES) WhB[(size_t)grow * OUT_FEAT + col] = f2bf(v);
            float ss = v * a_s;
            float st = v * a_t;
            #pragma unroll
            for (int off = 1; off < 16; off <<= 1) {   // reduce over 16-lane col group
                ss += __shfl_xor(ss, off, 64);
                st += __shfl_xor(st, off, 64);
            }
            if (cl == 0) { ssp[wid][lrow] = ss; stp[wid][lrow] = st; }
        }
    }
    __syncthreads();
    if (tid < 64 && r0 + tid < N_NODES) {
        s_src[r0 + tid] = (ssp[0][tid] + ssp[1][tid]) + (ssp[2][tid] + ssp[3][tid]);
        s_tgt[r0 + tid] = (stp[0][tid] + stp[1][tid]) + (stp[2][tid] + stp[3][tid]);
    }
}

// LDS-binned scatter: 4096 edges/block, one reserve atomic per (block,bucket),
// deposits packed (src | tgt_low<<17, e) into XCD-local sub-regions.  [proven]
__global__ __launch_bounds__(256) void scatter_kernel(
    const int* __restrict__ ei, const float* __restrict__ s_src,
    const float* __restrict__ s_tgt, int* __restrict__ cursorA,
    int2* __restrict__ bucketsA)
{
    __shared__ int hcnt[N_BKT];
    __shared__ int gbase[N_BKT];
    __shared__ int lcnt[N_BKT];
    const int tid = threadIdx.x;
    const int base = blockIdx.x * CH;
    const int sub = blockIdx.x & (N_SUB - 1);   // ~XCD id under round-robin dispatch

    for (int j = tid; j < N_BKT; j += 256) hcnt[j] = 0;
    __syncthreads();
    #pragma unroll
    for (int k = 0; k < CH / 256; ++k) {
        const int i = base + k * 256 + tid;
        if (i < N_EDGES) atomicAdd(&hcnt[ei[N_EDGES + i] >> BKT_SHIFT], 1);
    }
    __syncthreads();
    for (int j = tid; j < N_BKT; j += 256) {
        lcnt[j] = 0;
        const int c = hcnt[j];
        gbase[j] = c ? atomicAdd(&cursorA[j * N_SUB + sub], c) : 0;
    }
    __syncthreads();
    #pragma unroll
    for (int k = 0; k < CH / 256; ++k) {
        const int i = base + k * 256 + tid;
        if (i < N_EDGES) {
            const int s = ei[i];
            const int t = ei[N_EDGES + i];
            float v = s_src[s] + s_tgt[t];
            v = (v >= 0.0f) ? v : LRELU_SLOPE * v;
            const int bkt = t >> BKT_SHIFT;
            const int r = atomicAdd(&lcnt[bkt], 1);
            bucketsA[gbase[bkt] + r] =
                make_int2(s | ((t & (BKT_NODES - 1)) << 17), __float_as_int(v));
        }
    }
}

// One block per bucket: stage edges in LDS, per-node count+max, LDS scan,
// deposit (src, w=exp(v-m)), emit packed seg[node] = beg<<10 | cnt.
__global__ __launch_bounds__(256) void sort_bucket_kernel(
    const int* __restrict__ cursorA, const int2* __restrict__ bucketsA,
    int2* __restrict__ sorted_se, unsigned int* __restrict__ segA)
{
    __shared__ int2 stage[STAGE_CAP];     // 24 KB
    __shared__ int cnt[BKT_NODES];
    __shared__ int pfx[BKT_NODES];
    __shared__ int cur[BKT_NODES];
    __shared__ unsigned int m_enc[BKT_NODES];
    __shared__ int c_ofs[N_SUB + 1];
    const int b = blockIdx.x;
    const int tid = threadIdx.x;

    if (tid < BKT_NODES) { cnt[tid] = 0; m_enc[tid] = ENC_NEG_INF; }
    if (tid == 0) {
        int o = 0;
        #pragma unroll
        for (int s = 0; s < N_SUB; ++s) {
            c_ofs[s] = o;
            o += cursorA[b * N_SUB + s] - (b * N_SUB + s) * SUB_CAP;
        }
        c_ofs[N_SUB] = o;
    }
    __syncthreads();
    const int tot = c_ofs[N_SUB];
    #pragma unroll
    for (int s = 0; s < N_SUB; ++s) {
        const int o = c_ofs[s];
        const int c = c_ofs[s + 1] - o;
        const int2* src = bucketsA + (size_t)(b * N_SUB + s) * SUB_CAP;
        for (int k = tid; k < c; k += 256) stage[o + k] = src[k];
    }
    __syncthreads();
    for (int i = tid; i < tot; i += 256) {
        const int2 pk = stage[i];
        const int tl = (pk.x >> 17) & (BKT_NODES - 1);
        atomicAdd(&cnt[tl], 1);
        atomicMax(&m_enc[tl], enc_f(__int_as_float(pk.y)));
    }
    __syncthreads();
    if (tid < BKT_NODES) pfx[tid] = cnt[tid];
    __syncthreads();
    for (int off = 1; off < BKT_NODES; off <<= 1) {
        int add = (tid < BKT_NODES && tid >= off) ? pfx[tid - off] : 0;
        __syncthreads();
        if (tid < BKT_NODES) pfx[tid] += add;
        __syncthreads();
    }
    if (tid < BKT_NODES) {
        const int ex = pfx[tid] - cnt[tid];    // exclusive
        cur[tid] = ex;
        const int node = b * BKT_NODES + tid;
        if (node < N_NODES)
            segA[node] = ((unsigned int)(b * STAGE_CAP + ex) << 10) | (unsigned int)cnt[tid];
    }
    __syncthreads();
    for (int i = tid; i < tot; i += 256) {
        const int2 pk = stage[i];
        const int tl = (pk.x >> 17) & (BKT_NODES - 1);
        const int pos = atomicAdd(&cur[tl], 1);
        const float w = __expf(__int_as_float(pk.y) - dec_f(m_enc[tl]));
        sorted_se[(size_t)b * STAGE_CAP + pos] = make_int2(pk.x & 0x1FFFF, __float_as_int(w));
    }
}

// Single-pass: acc[f] = sum_e w_e * Wh[src_e][f], sum = sum_e w_e (wave-uniform),
// out = elu(acc/(sum+eps)).  One wave per node; lane = feature.
__global__ __launch_bounds__(256) void node_aggr_kernel(
    const unsigned int* __restrict__ segA, const int2* __restrict__ sorted_se,
    const unsigned short* __restrict__ WhB, float* __restrict__ out)
{
    const int wid = (blockIdx.x * 256 + threadIdx.x) >> 6;   // node id
    const int lane = threadIdx.x & 63;
    if (wid >= N_NODES) return;
    const unsigned int sg = segA[wid];
    const int beg = (int)(sg >> 10);
    const int end = beg + (int)(sg & 1023u);

    float acc = 0.0f, sum = 0.0f;
    int i = beg;
    for (; i + 4 <= end; i += 4) {
        const int2 p0 = sorted_se[i],     p1 = sorted_se[i + 1];
        const int2 p2 = sorted_se[i + 2], p3 = sorted_se[i + 3];
        const float g0 = __uint_as_float((unsigned int)WhB[(size_t)p0.x * OUT_FEAT + lane] << 16);
        const float g1 = __uint_as_float((unsigned int)WhB[(size_t)p1.x * OUT_FEAT + lane] << 16);
        const float g2 = __uint_as_float((unsigned int)WhB[(size_t)p2.x * OUT_FEAT + lane] << 16);
        const float g3 = __uint_as_float((unsigned int)WhB[(size_t)p3.x * OUT_FEAT + lane] << 16);
        const float w0 = __int_as_float(p0.y), w1 = __int_as_float(p1.y);
        const float w2 = __int_as_float(p2.y), w3 = __int_as_float(p3.y);
        acc += w0 * g0 + w1 * g1 + w2 * g2 + w3 * g3;
        sum += (w0 + w1) + (w2 + w3);
    }
    for (; i < end; ++i) {
        const int2 pk = sorted_se[i];
        const float w = __int_as_float(pk.y);
        const float g = __uint_as_float((unsigned int)WhB[(size_t)pk.x * OUT_FEAT + lane] << 16);
        acc += w * g;
        sum += w;
    }

    const float val = acc / (sum + EPS_DENOM);
    out[(size_t)wid * OUT_FEAT + lane] = (val > 0.0f) ? val : expm1f(val);
}

extern "C" void kernel_launch(void* const* d_in, const int* in_sizes, int n_in,
                              void* d_out, int out_size, void* d_ws, size_t ws_size,
                              hipStream_t stream) {
    const float* x  = (const float*)d_in[0];
    const int*   ei = (const int*)d_in[1];     // int64 in reference -> int32 on device
    const float* W  = (const float*)d_in[2];
    const float* a  = (const float*)d_in[3];
    float* out = (float*)d_out;

    // workspace (~53 MB)
    char* p = (char*)d_ws;
    unsigned short* WhB = (unsigned short*)p; p += (size_t)N_NODES * OUT_FEAT * 2; // 12.8 MB
    unsigned short* WTb = (unsigned short*)p; p += (size_t)OUT_FEAT * IN_FEAT * 2; // 16 KB
    float* s_src    = (float*)p;  p += (size_t)N_NODES * 4;
    float* s_tgt    = (float*)p;  p += (size_t)N_NODES * 4;
    unsigned int* segA = (unsigned int*)p; p += (size_t)N_NODES * 4;
    int*   cursorA  = (int*)p;    p += (size_t)N_BKT * N_SUB * 4;
    p = (char*)(((size_t)p + 15) & ~(size_t)15);
    int2*  bucketsA = (int2*)p;   p += (size_t)N_BKT * N_SUB * SUB_CAP * 8;        // 19.2 MB
    int2*  sorted_se = (int2*)p;  p += (size_t)N_BKT * STAGE_CAP * 8;              // 19.2 MB

    init_prep_kernel<<<32, 256, 0, stream>>>(W, cursorA, WTb);
    gemm_mfma_kernel<<<(N_NODES + 63) / 64, 256, 0, stream>>>(x, WTb, a, WhB, s_src, s_tgt);
    scatter_kernel<<<SCAT_BLOCKS, 256, 0, stream>>>(ei, s_src, s_tgt, cursorA, bucketsA);
    sort_bucket_kernel<<<N_BKT, 256, 0, stream>>>(cursorA, bucketsA, sorted_se, segA);
    node_aggr_kernel<<<(N_NODES * 64 + 255) / 256, 256, 0, stream>>>(segA, sorted_se, WhB, out);
}

// Round 9
// 152.103 us; speedup vs baseline: 5.6638x; 1.0180x over previous
//
#include <hip/hip_runtime.h>

#define N_NODES 100000
#define N_EDGES 1600000
#define IN_FEAT 128
#define OUT_FEAT 64
#define LRELU_SLOPE 0.2f
#define EPS_DENOM 1e-16f

#define BKT_SHIFT 7
#define BKT_NODES 128
#define N_BKT ((N_NODES + BKT_NODES - 1) / BKT_NODES)   // 782
#define N_SUB 8
#define SUB_CAP 384                                      // mean 256/sub, ~8 sigma headroom
#define STAGE_CAP (N_SUB * SUB_CAP)                      // 3072 (mean 2048/bucket)
#define CH 4096                                          // edges per scatter block
#define SCAT_BLOCKS ((N_EDGES + CH - 1) / CH)            // 391

typedef __attribute__((ext_vector_type(8))) short bf16x8;
typedef __attribute__((ext_vector_type(4))) float f32x4;

// ---- float atomic-max via order-preserving uint encoding ----
__device__ __forceinline__ unsigned int enc_f(float x) {
    unsigned int u = __float_as_uint(x);
    return (u & 0x80000000u) ? ~u : (u | 0x80000000u);
}
__device__ __forceinline__ float dec_f(unsigned int u) {
    u = (u & 0x80000000u) ? (u ^ 0x80000000u) : ~u;
    return __uint_as_float(u);
}
#define ENC_NEG_INF 0x007FFFFFu

__device__ __forceinline__ unsigned short f2bf(float f) {   // RNE
    unsigned int u = __float_as_uint(f);
    u = (u + 0x7FFFu + ((u >> 16) & 1u)) >> 16;
    return (unsigned short)u;
}

// init cursorA + convert W -> bf16 transposed WT[n][k]
__global__ __launch_bounds__(256) void init_prep_kernel(
    const float* __restrict__ W, int* __restrict__ cursorA,
    unsigned short* __restrict__ WTb)
{
    const int i = blockIdx.x * 256 + threadIdx.x;
    if (i < N_BKT * N_SUB) cursorA[i] = i * SUB_CAP;     // static sub-region starts
    if (i < OUT_FEAT * IN_FEAT) {
        const int n = i >> 7, k = i & 127;
        WTb[i] = f2bf(W[k * OUT_FEAT + n]);
    }
}

// MFMA GEMM: Wh(bf16) = x @ W, fused s_src/s_tgt epilogue (fp32 acc).
// Block = 64 rows x 64 cols, 4 waves; wave w: 16-col strip, 4 M-tiles.
__global__ __launch_bounds__(256) void gemm_mfma_kernel(
    const float* __restrict__ x, const unsigned short* __restrict__ WTb,
    const float* __restrict__ a, unsigned short* __restrict__ WhB,
    float* __restrict__ s_src, float* __restrict__ s_tgt)
{
    __shared__ __align__(16) unsigned short xs[64][136];   // +8 pad: bank spread
    __shared__ float ssp[4][64], stp[4][64];
    const int tid = threadIdx.x;
    const int wid = tid >> 6, lane = tid & 63;
    const int r0 = blockIdx.x * 64;

    // stage 64x128 fp32 -> bf16 LDS (8 float4 per thread)
    #pragma unroll
    for (int it = 0; it < 8; ++it) {
        const int idx4 = it * 256 + tid;       // float4 index 0..2047
        const int row = idx4 >> 5;             // 32 float4 per row
        const int col = (idx4 & 31) * 4;
        float4 v = make_float4(0.f, 0.f, 0.f, 0.f);
        if (r0 + row < N_NODES) v = *(const float4*)(x + (size_t)(r0 + row) * IN_FEAT + col);
        const unsigned int p0 = (unsigned int)f2bf(v.x) | ((unsigned int)f2bf(v.y) << 16);
        const unsigned int p1 = (unsigned int)f2bf(v.z) | ((unsigned int)f2bf(v.w) << 16);
        *(uint2*)&xs[row][col] = make_uint2(p0, p1);
    }
    __syncthreads();

    const int cgrp = lane >> 4;          // k-subgroup 0..3
    const int cl = lane & 15;
    const int col = wid * 16 + cl;       // output col (N dim)
    f32x4 acc0 = {0.f,0.f,0.f,0.f}, acc1 = acc0, acc2 = acc0, acc3 = acc0;
    #pragma unroll
    for (int kb = 0; kb < IN_FEAT; kb += 32) {
        const bf16x8 bfrag = *(const bf16x8*)(WTb + col * IN_FEAT + kb + cgrp * 8);
        const bf16x8 a0 = *(const bf16x8*)&xs[ 0 + cl][kb + cgrp * 8];
        const bf16x8 a1 = *(const bf16x8*)&xs[16 + cl][kb + cgrp * 8];
        const bf16x8 a2 = *(const bf16x8*)&xs[32 + cl][kb + cgrp * 8];
        const bf16x8 a3 = *(const bf16x8*)&xs[48 + cl][kb + cgrp * 8];
        acc0 = __builtin_amdgcn_mfma_f32_16x16x32_bf16(a0, bfrag, acc0, 0, 0, 0);
        acc1 = __builtin_amdgcn_mfma_f32_16x16x32_bf16(a1, bfrag, acc1, 0, 0, 0);
        acc2 = __builtin_amdgcn_mfma_f32_16x16x32_bf16(a2, bfrag, acc2, 0, 0, 0);
        acc3 = __builtin_amdgcn_mfma_f32_16x16x32_bf16(a3, bfrag, acc3, 0, 0, 0);
    }

    // epilogue: C/D layout col=lane&15, row=(lane>>4)*4+reg
    const float a_s = a[col], a_t = a[OUT_FEAT + col];
    #pragma unroll
    for (int mt = 0; mt < 4; ++mt) {
        const f32x4 av = (mt == 0) ? acc0 : (mt == 1) ? acc1 : (mt == 2) ? acc2 : acc3;
        #pragma unroll
        for (int r = 0; r < 4; ++r) {
            const int lrow = mt * 16 + cgrp * 4 + r;
            const float v = av[r];
            const int grow = r0 + lrow;
            if (grow < N_NODES) WhB[(size_t)grow * OUT_FEAT + col] = f2bf(v);
            float ss = v * a_s;
            float st = v * a_t;
            #pragma unroll
            for (int off = 1; off < 16; off <<= 1) {   // reduce over 16-lane col group
                ss += __shfl_xor(ss, off, 64);
                st += __shfl_xor(st, off, 64);
            }
            if (cl == 0) { ssp[wid][lrow] = ss; stp[wid][lrow] = st; }
        }
    }
    __syncthreads();
    if (tid < 64 && r0 + tid < N_NODES) {
        s_src[r0 + tid] = (ssp[0][tid] + ssp[1][tid]) + (ssp[2][tid] + ssp[3][tid]);
        s_tgt[r0 + tid] = (stp[0][tid] + stp[1][tid]) + (stp[2][tid] + stp[3][tid]);
    }
}

// LDS-binned scatter: 4096 edges/block, one reserve atomic per (block,bucket),
// deposits packed (src | tgt_low<<17, e) into XCD-local sub-regions.  [proven]
__global__ __launch_bounds__(256) void scatter_kernel(
    const int* __restrict__ ei, const float* __restrict__ s_src,
    const float* __restrict__ s_tgt, int* __restrict__ cursorA,
    int2* __restrict__ bucketsA)
{
    __shared__ int hcnt[N_BKT];
    __shared__ int gbase[N_BKT];
    __shared__ int lcnt[N_BKT];
    const int tid = threadIdx.x;
    const int base = blockIdx.x * CH;
    const int sub = blockIdx.x & (N_SUB - 1);   // ~XCD id under round-robin dispatch

    for (int j = tid; j < N_BKT; j += 256) hcnt[j] = 0;
    __syncthreads();
    #pragma unroll
    for (int k = 0; k < CH / 256; ++k) {
        const int i = base + k * 256 + tid;
        if (i < N_EDGES) atomicAdd(&hcnt[ei[N_EDGES + i] >> BKT_SHIFT], 1);
    }
    __syncthreads();
    for (int j = tid; j < N_BKT; j += 256) {
        lcnt[j] = 0;
        const int c = hcnt[j];
        gbase[j] = c ? atomicAdd(&cursorA[j * N_SUB + sub], c) : 0;
    }
    __syncthreads();
    #pragma unroll
    for (int k = 0; k < CH / 256; ++k) {
        const int i = base + k * 256 + tid;
        if (i < N_EDGES) {
            const int s = ei[i];
            const int t = ei[N_EDGES + i];
            float v = s_src[s] + s_tgt[t];
            v = (v >= 0.0f) ? v : LRELU_SLOPE * v;
            const int bkt = t >> BKT_SHIFT;
            const int r = atomicAdd(&lcnt[bkt], 1);
            bucketsA[gbase[bkt] + r] =
                make_int2(s | ((t & (BKT_NODES - 1)) << 17), __float_as_int(v));
        }
    }
}

// One block per bucket: stage edges in LDS, per-node count+max, LDS scan
// (segment starts EVEN-aligned for int4 paired reads downstream),
// deposit (src, w=exp(v-m)), emit packed seg[node] = beg<<10 | cnt.
__global__ __launch_bounds__(256) void sort_bucket_kernel(
    const int* __restrict__ cursorA, const int2* __restrict__ bucketsA,
    int2* __restrict__ sorted_se, unsigned int* __restrict__ segA)
{
    __shared__ int2 stage[STAGE_CAP];     // 24 KB
    __shared__ int cnt[BKT_NODES];
    __shared__ int pfx[BKT_NODES];
    __shared__ int cur[BKT_NODES];
    __shared__ unsigned int m_enc[BKT_NODES];
    __shared__ int c_ofs[N_SUB + 1];
    const int b = blockIdx.x;
    const int tid = threadIdx.x;

    if (tid < BKT_NODES) { cnt[tid] = 0; m_enc[tid] = ENC_NEG_INF; }
    if (tid == 0) {
        int o = 0;
        #pragma unroll
        for (int s = 0; s < N_SUB; ++s) {
            c_ofs[s] = o;
            o += cursorA[b * N_SUB + s] - (b * N_SUB + s) * SUB_CAP;
        }
        c_ofs[N_SUB] = o;
    }
    __syncthreads();
    const int tot = c_ofs[N_SUB];
    #pragma unroll
    for (int s = 0; s < N_SUB; ++s) {
        const int o = c_ofs[s];
        const int c = c_ofs[s + 1] - o;
        const int2* src = bucketsA + (size_t)(b * N_SUB + s) * SUB_CAP;
        for (int k = tid; k < c; k += 256) stage[o + k] = src[k];
    }
    __syncthreads();
    for (int i = tid; i < tot; i += 256) {
        const int2 pk = stage[i];
        const int tl = (pk.x >> 17) & (BKT_NODES - 1);
        atomicAdd(&cnt[tl], 1);
        atomicMax(&m_enc[tl], enc_f(__int_as_float(pk.y)));
    }
    __syncthreads();
    // inclusive scan over EVEN-PADDED counts (Hillis-Steele)
    if (tid < BKT_NODES) pfx[tid] = (cnt[tid] + 1) & ~1;
    __syncthreads();
    for (int off = 1; off < BKT_NODES; off <<= 1) {
        int add = (tid < BKT_NODES && tid >= off) ? pfx[tid - off] : 0;
        __syncthreads();
        if (tid < BKT_NODES) pfx[tid] += add;
        __syncthreads();
    }
    if (tid < BKT_NODES) {
        const int ex = pfx[tid] - ((cnt[tid] + 1) & ~1);    // exclusive, even
        cur[tid] = ex;
        const int node = b * BKT_NODES + tid;
        if (node < N_NODES)
            segA[node] = ((unsigned int)(b * STAGE_CAP + ex) << 10) | (unsigned int)cnt[tid];
    }
    __syncthreads();
    for (int i = tid; i < tot; i += 256) {
        const int2 pk = stage[i];
        const int tl = (pk.x >> 17) & (BKT_NODES - 1);
        const int pos = atomicAdd(&cur[tl], 1);
        const float w = __expf(__int_as_float(pk.y) - dec_f(m_enc[tl]));
        sorted_se[(size_t)b * STAGE_CAP + pos] = make_int2(pk.x & 0x1FFFF, __float_as_int(w));
    }
}

// Paired single-pass aggregation: lanes 0-31 handle edge e, lanes 32-63 edge e+1
// (one dword gather covers 2 bf16 features/lane); int4 broadcast loads of (src,w);
// cross-half combine via shfl_xor(32); out = elu(acc/(sum+eps)).
__global__ __launch_bounds__(256) void node_aggr_kernel(
    const unsigned int* __restrict__ segA, const int2* __restrict__ sorted_se,
    const unsigned short* __restrict__ WhB, float* __restrict__ out)
{
    const int wid = (blockIdx.x * 256 + threadIdx.x) >> 6;   // node id
    const int lane = threadIdx.x & 63;
    if (wid >= N_NODES) return;
    const unsigned int sg = segA[wid];
    const int beg = (int)(sg >> 10);          // even-aligned
    const int end = beg + (int)(sg & 1023u);
    const int hl = lane & 31;
    const bool hi = lane >= 32;
    const char* whb = (const char*)WhB;
    const unsigned int foff = (unsigned int)hl << 2;   // byte offset in 128 B row

    float accx = 0.f, accy = 0.f, sum = 0.f;
    int i = beg;
    for (; i + 4 <= end; i += 4) {
        const int4 q0 = *(const int4*)&sorted_se[i];       // edges i, i+1
        const int4 q1 = *(const int4*)&sorted_se[i + 2];   // edges i+2, i+3
        const unsigned int s0 = (unsigned int)(hi ? q0.z : q0.x);
        const unsigned int s1 = (unsigned int)(hi ? q1.z : q1.x);
        const float w0 = __int_as_float(hi ? q0.w : q0.y);
        const float w1 = __int_as_float(hi ? q1.w : q1.y);
        const unsigned int g0 = *(const unsigned int*)(whb + ((s0 << 7) + foff));
        const unsigned int g1 = *(const unsigned int*)(whb + ((s1 << 7) + foff));
        accx += w0 * __uint_as_float(g0 << 16);
        accy += w0 * __uint_as_float(g0 & 0xFFFF0000u);
        accx += w1 * __uint_as_float(g1 << 16);
        accy += w1 * __uint_as_float(g1 & 0xFFFF0000u);
        sum += w0 + w1;
    }
    if (i + 2 <= end) {
        const int4 q0 = *(const int4*)&sorted_se[i];
        const unsigned int s0 = (unsigned int)(hi ? q0.z : q0.x);
        const float w0 = __int_as_float(hi ? q0.w : q0.y);
        const unsigned int g0 = *(const unsigned int*)(whb + ((s0 << 7) + foff));
        accx += w0 * __uint_as_float(g0 << 16);
        accy += w0 * __uint_as_float(g0 & 0xFFFF0000u);
        sum += w0;
        i += 2;
    }
    if (i < end) {   // odd tail: lo half carries it, hi half weight 0
        const int2 pk = sorted_se[i];
        const float w0 = hi ? 0.f : __int_as_float(pk.y);
        const unsigned int g0 = *(const unsigned int*)(whb + (((unsigned int)pk.x << 7) + foff));
        accx += w0 * __uint_as_float(g0 << 16);
        accy += w0 * __uint_as_float(g0 & 0xFFFF0000u);
        sum += w0;
    }

    accx += __shfl_xor(accx, 32, 64);
    accy += __shfl_xor(accy, 32, 64);
    sum  += __shfl_xor(sum, 32, 64);
    if (!hi) {
        const float inv = 1.0f / (sum + EPS_DENOM);
        float vx = accx * inv, vy = accy * inv;
        vx = (vx > 0.f) ? vx : expm1f(vx);
        vy = (vy > 0.f) ? vy : expm1f(vy);
        *(float2*)(out + (size_t)wid * OUT_FEAT + (hl << 1)) = make_float2(vx, vy);
    }
}

extern "C" void kernel_launch(void* const* d_in, const int* in_sizes, int n_in,
                              void* d_out, int out_size, void* d_ws, size_t ws_size,
                              hipStream_t stream) {
    const float* x  = (const float*)d_in[0];
    const int*   ei = (const int*)d_in[1];     // int64 in reference -> int32 on device
    const float* W  = (const float*)d_in[2];
    const float* a  = (const float*)d_in[3];
    float* out = (float*)d_out;

    // workspace (~53 MB)
    char* p = (char*)d_ws;
    unsigned short* WhB = (unsigned short*)p; p += (size_t)N_NODES * OUT_FEAT * 2; // 12.8 MB
    unsigned short* WTb = (unsigned short*)p; p += (size_t)OUT_FEAT * IN_FEAT * 2; // 16 KB
    float* s_src    = (float*)p;  p += (size_t)N_NODES * 4;
    float* s_tgt    = (float*)p;  p += (size_t)N_NODES * 4;
    unsigned int* segA = (unsigned int*)p; p += (size_t)N_NODES * 4;
    int*   cursorA  = (int*)p;    p += (size_t)N_BKT * N_SUB * 4;
    p = (char*)(((size_t)p + 15) & ~(size_t)15);
    int2*  bucketsA = (int2*)p;   p += (size_t)N_BKT * N_SUB * SUB_CAP * 8;        // 19.2 MB
    int2*  sorted_se = (int2*)p;  p += (size_t)N_BKT * STAGE_CAP * 8;              // 19.2 MB

    init_prep_kernel<<<32, 256, 0, stream>>>(W, cursorA, WTb);
    gemm_mfma_kernel<<<(N_NODES + 63) / 64, 256, 0, stream>>>(x, WTb, a, WhB, s_src, s_tgt);
    scatter_kernel<<<SCAT_BLOCKS, 256, 0, stream>>>(ei, s_src, s_tgt, cursorA, bucketsA);
    sort_bucket_kernel<<<N_BKT, 256, 0, stream>>>(cursorA, bucketsA, sorted_se, segA);
    node_aggr_kernel<<<(N_NODES * 64 + 255) / 256, 256, 0, stream>>>(segA, sorted_se, WhB, out);
}

// Round 10
// 148.309 us; speedup vs baseline: 5.8087x; 1.0256x over previous
//
#include <hip/hip_runtime.h>

#define N_NODES 100000
#define N_EDGES 1600000
#define IN_FEAT 128
#define OUT_FEAT 64
#define LRELU_SLOPE 0.2f
#define EPS_DENOM 1e-16f

#define BKT_SHIFT 7
#define BKT_NODES 128
#define N_BKT ((N_NODES + BKT_NODES - 1) / BKT_NODES)   // 782
#define N_SUB 8
#define SUB_CAP 384                                      // mean 256/sub, ~8 sigma headroom
#define STAGE_CAP (N_SUB * SUB_CAP)                      // 3072 (mean 2048/bucket)
#define CH 4096                                          // edges per scatter block
#define SCAT_BLOCKS ((N_EDGES + CH - 1) / CH)            // 391

typedef __attribute__((ext_vector_type(8))) short bf16x8;
typedef __attribute__((ext_vector_type(4))) float f32x4;

// ---- float atomic-max via order-preserving uint encoding ----
__device__ __forceinline__ unsigned int enc_f(float x) {
    unsigned int u = __float_as_uint(x);
    return (u & 0x80000000u) ? ~u : (u | 0x80000000u);
}
__device__ __forceinline__ float dec_f(unsigned int u) {
    u = (u & 0x80000000u) ? (u ^ 0x80000000u) : ~u;
    return __uint_as_float(u);
}
#define ENC_NEG_INF 0x007FFFFFu

__device__ __forceinline__ unsigned short f2bf(float f) {   // RNE
    unsigned int u = __float_as_uint(f);
    u = (u + 0x7FFFu + ((u >> 16) & 1u)) >> 16;
    return (unsigned short)u;
}

// init cursorA + convert W -> bf16 transposed WT[n][k]
__global__ __launch_bounds__(256) void init_prep_kernel(
    const float* __restrict__ W, int* __restrict__ cursorA,
    unsigned short* __restrict__ WTb)
{
    const int i = blockIdx.x * 256 + threadIdx.x;
    if (i < N_BKT * N_SUB) cursorA[i] = i * SUB_CAP;     // static sub-region starts
    if (i < OUT_FEAT * IN_FEAT) {
        const int n = i >> 7, k = i & 127;
        WTb[i] = f2bf(W[k * OUT_FEAT + n]);
    }
}

// MFMA GEMM: Wh(bf16) = x @ W, fused s_src/s_tgt epilogue (fp32 acc).
// Block = 64 rows x 64 cols, 4 waves; wave w: 16-col strip, 4 M-tiles.
__global__ __launch_bounds__(256) void gemm_mfma_kernel(
    const float* __restrict__ x, const unsigned short* __restrict__ WTb,
    const float* __restrict__ a, unsigned short* __restrict__ WhB,
    float* __restrict__ s_src, float* __restrict__ s_tgt)
{
    __shared__ __align__(16) unsigned short xs[64][136];   // +8 pad: bank spread
    __shared__ float ssp[4][64], stp[4][64];
    const int tid = threadIdx.x;
    const int wid = tid >> 6, lane = tid & 63;
    const int r0 = blockIdx.x * 64;

    // stage 64x128 fp32 -> bf16 LDS (8 float4 per thread)
    #pragma unroll
    for (int it = 0; it < 8; ++it) {
        const int idx4 = it * 256 + tid;       // float4 index 0..2047
        const int row = idx4 >> 5;             // 32 float4 per row
        const int col = (idx4 & 31) * 4;
        float4 v = make_float4(0.f, 0.f, 0.f, 0.f);
        if (r0 + row < N_NODES) v = *(const float4*)(x + (size_t)(r0 + row) * IN_FEAT + col);
        const unsigned int p0 = (unsigned int)f2bf(v.x) | ((unsigned int)f2bf(v.y) << 16);
        const unsigned int p1 = (unsigned int)f2bf(v.z) | ((unsigned int)f2bf(v.w) << 16);
        *(uint2*)&xs[row][col] = make_uint2(p0, p1);
    }
    __syncthreads();

    const int cgrp = lane >> 4;          // k-subgroup 0..3
    const int cl = lane & 15;
    const int col = wid * 16 + cl;       // output col (N dim)
    f32x4 acc0 = {0.f,0.f,0.f,0.f}, acc1 = acc0, acc2 = acc0, acc3 = acc0;
    #pragma unroll
    for (int kb = 0; kb < IN_FEAT; kb += 32) {
        const bf16x8 bfrag = *(const bf16x8*)(WTb + col * IN_FEAT + kb + cgrp * 8);
        const bf16x8 a0 = *(const bf16x8*)&xs[ 0 + cl][kb + cgrp * 8];
        const bf16x8 a1 = *(const bf16x8*)&xs[16 + cl][kb + cgrp * 8];
        const bf16x8 a2 = *(const bf16x8*)&xs[32 + cl][kb + cgrp * 8];
        const bf16x8 a3 = *(const bf16x8*)&xs[48 + cl][kb + cgrp * 8];
        acc0 = __builtin_amdgcn_mfma_f32_16x16x32_bf16(a0, bfrag, acc0, 0, 0, 0);
        acc1 = __builtin_amdgcn_mfma_f32_16x16x32_bf16(a1, bfrag, acc1, 0, 0, 0);
        acc2 = __builtin_amdgcn_mfma_f32_16x16x32_bf16(a2, bfrag, acc2, 0, 0, 0);
        acc3 = __builtin_amdgcn_mfma_f32_16x16x32_bf16(a3, bfrag, acc3, 0, 0, 0);
    }

    // epilogue: C/D layout col=lane&15, row=(lane>>4)*4+reg
    const float a_s = a[col], a_t = a[OUT_FEAT + col];
    #pragma unroll
    for (int mt = 0; mt < 4; ++mt) {
        const f32x4 av = (mt == 0) ? acc0 : (mt == 1) ? acc1 : (mt == 2) ? acc2 : acc3;
        #pragma unroll
        for (int r = 0; r < 4; ++r) {
            const int lrow = mt * 16 + cgrp * 4 + r;
            const float v = av[r];
            const int grow = r0 + lrow;
            if (grow < N_NODES) WhB[(size_t)grow * OUT_FEAT + col] = f2bf(v);
            float ss = v * a_s;
            float st = v * a_t;
            #pragma unroll
            for (int off = 1; off < 16; off <<= 1) {   // reduce over 16-lane col group
                ss += __shfl_xor(ss, off, 64);
                st += __shfl_xor(st, off, 64);
            }
            if (cl == 0) { ssp[wid][lrow] = ss; stp[wid][lrow] = st; }
        }
    }
    __syncthreads();
    if (tid < 64 && r0 + tid < N_NODES) {
        s_src[r0 + tid] = (ssp[0][tid] + ssp[1][tid]) + (ssp[2][tid] + ssp[3][tid]);
        s_tgt[r0 + tid] = (stp[0][tid] + stp[1][tid]) + (stp[2][tid] + stp[3][tid]);
    }
}

// LDS-binned scatter, now 512 threads/block for 2x wave-level latency hiding.
// Same CH=4096 (write-run length preserved), one reserve atomic per (block,bucket).
__global__ __launch_bounds__(512) void scatter_kernel(
    const int* __restrict__ ei, const float* __restrict__ s_src,
    const float* __restrict__ s_tgt, int* __restrict__ cursorA,
    int2* __restrict__ bucketsA)
{
    __shared__ int hcnt[N_BKT];
    __shared__ int gbase[N_BKT];
    __shared__ int lcnt[N_BKT];
    const int tid = threadIdx.x;
    const int base = blockIdx.x * CH;
    const int sub = blockIdx.x & (N_SUB - 1);   // ~XCD id under round-robin dispatch

    for (int j = tid; j < N_BKT; j += 512) hcnt[j] = 0;
    __syncthreads();
    #pragma unroll
    for (int k = 0; k < CH / 512; ++k) {
        const int i = base + k * 512 + tid;
        if (i < N_EDGES) atomicAdd(&hcnt[ei[N_EDGES + i] >> BKT_SHIFT], 1);
    }
    __syncthreads();
    for (int j = tid; j < N_BKT; j += 512) {
        lcnt[j] = 0;
        const int c = hcnt[j];
        gbase[j] = c ? atomicAdd(&cursorA[j * N_SUB + sub], c) : 0;
    }
    __syncthreads();
    #pragma unroll
    for (int k = 0; k < CH / 512; ++k) {
        const int i = base + k * 512 + tid;
        if (i < N_EDGES) {
            const int s = ei[i];
            const int t = ei[N_EDGES + i];
            float v = s_src[s] + s_tgt[t];
            v = (v >= 0.0f) ? v : LRELU_SLOPE * v;
            const int bkt = t >> BKT_SHIFT;
            const int r = atomicAdd(&lcnt[bkt], 1);
            bucketsA[gbase[bkt] + r] =
                make_int2(s | ((t & (BKT_NODES - 1)) << 17), __float_as_int(v));
        }
    }
}

// One block per bucket: stage edges in LDS, per-node count+max, LDS scan,
// deposit (src, w=exp(v-m)), emit packed seg[node] = beg<<10 | cnt.
__global__ __launch_bounds__(256) void sort_bucket_kernel(
    const int* __restrict__ cursorA, const int2* __restrict__ bucketsA,
    int2* __restrict__ sorted_se, unsigned int* __restrict__ segA)
{
    __shared__ int2 stage[STAGE_CAP];     // 24 KB
    __shared__ int cnt[BKT_NODES];
    __shared__ int pfx[BKT_NODES];
    __shared__ int cur[BKT_NODES];
    __shared__ unsigned int m_enc[BKT_NODES];
    __shared__ int c_ofs[N_SUB + 1];
    const int b = blockIdx.x;
    const int tid = threadIdx.x;

    if (tid < BKT_NODES) { cnt[tid] = 0; m_enc[tid] = ENC_NEG_INF; }
    if (tid == 0) {
        int o = 0;
        #pragma unroll
        for (int s = 0; s < N_SUB; ++s) {
            c_ofs[s] = o;
            o += cursorA[b * N_SUB + s] - (b * N_SUB + s) * SUB_CAP;
        }
        c_ofs[N_SUB] = o;
    }
    __syncthreads();
    const int tot = c_ofs[N_SUB];
    #pragma unroll
    for (int s = 0; s < N_SUB; ++s) {
        const int o = c_ofs[s];
        const int c = c_ofs[s + 1] - o;
        const int2* src = bucketsA + (size_t)(b * N_SUB + s) * SUB_CAP;
        for (int k = tid; k < c; k += 256) stage[o + k] = src[k];
    }
    __syncthreads();
    for (int i = tid; i < tot; i += 256) {
        const int2 pk = stage[i];
        const int tl = (pk.x >> 17) & (BKT_NODES - 1);
        atomicAdd(&cnt[tl], 1);
        atomicMax(&m_enc[tl], enc_f(__int_as_float(pk.y)));
    }
    __syncthreads();
    if (tid < BKT_NODES) pfx[tid] = cnt[tid];
    __syncthreads();
    for (int off = 1; off < BKT_NODES; off <<= 1) {
        int add = (tid < BKT_NODES && tid >= off) ? pfx[tid - off] : 0;
        __syncthreads();
        if (tid < BKT_NODES) pfx[tid] += add;
        __syncthreads();
    }
    if (tid < BKT_NODES) {
        const int ex = pfx[tid] - cnt[tid];    // exclusive
        cur[tid] = ex;
        const int node = b * BKT_NODES + tid;
        if (node < N_NODES)
            segA[node] = ((unsigned int)(b * STAGE_CAP + ex) << 10) | (unsigned int)cnt[tid];
    }
    __syncthreads();
    for (int i = tid; i < tot; i += 256) {
        const int2 pk = stage[i];
        const int tl = (pk.x >> 17) & (BKT_NODES - 1);
        const int pos = atomicAdd(&cur[tl], 1);
        const float w = __expf(__int_as_float(pk.y) - dec_f(m_enc[tl]));
        sorted_se[(size_t)b * STAGE_CAP + pos] = make_int2(pk.x & 0x1FFFF, __float_as_int(w));
    }
}

// 4 nodes per wave, 16 lanes per node, 4 features per lane (uint2 gather).
// Each lane owns its 4 features end-to-end: no cross-lane reduce, no selects.
__global__ __launch_bounds__(256) void node_aggr_kernel(
    const unsigned int* __restrict__ segA, const int2* __restrict__ sorted_se,
    const unsigned short* __restrict__ WhB, float* __restrict__ out)
{
    const int gtid = blockIdx.x * 256 + threadIdx.x;
    const int node = gtid >> 4;              // 16 lanes per node
    const int gl = threadIdx.x & 15;
    // grid sized exactly: N_NODES*16 threads, no partial waves
    const unsigned int sg = segA[node];
    int idx = (int)(sg >> 10);
    const int len = (int)(sg & 1023u);
    const int end = idx + len;

    // wave-uniform trip count = max over the 4 groups in this wave
    int mx = len;
    mx = max(mx, __shfl_xor(mx, 16, 64));
    mx = max(mx, __shfl_xor(mx, 32, 64));

    const char* whb = (const char*)WhB;
    const unsigned int foff = (unsigned int)gl << 3;   // 8 B (4 bf16 feats) per lane
    float a0 = 0.f, a1 = 0.f, a2 = 0.f, a3 = 0.f, sum = 0.f;
    for (int it = 0; it < mx; ++it, ++idx) {
        const int2 pk = sorted_se[idx];                     // broadcast within group
        const float w = (idx < end) ? __int_as_float(pk.y) : 0.f;
        const unsigned int s = (unsigned int)pk.x & 0x1FFFFu;   // poison-safe mask
        const uint2 g = *(const uint2*)(whb + ((s << 7) + foff));
        a0 += w * __uint_as_float(g.x << 16);
        a1 += w * __uint_as_float(g.x & 0xFFFF0000u);
        a2 += w * __uint_as_float(g.y << 16);
        a3 += w * __uint_as_float(g.y & 0xFFFF0000u);
        sum += w;
    }

    const float inv = 1.0f / (sum + EPS_DENOM);
    float4 o;
    o.x = a0 * inv; o.y = a1 * inv; o.z = a2 * inv; o.w = a3 * inv;
    o.x = (o.x > 0.f) ? o.x : expm1f(o.x);
    o.y = (o.y > 0.f) ? o.y : expm1f(o.y);
    o.z = (o.z > 0.f) ? o.z : expm1f(o.z);
    o.w = (o.w > 0.f) ? o.w : expm1f(o.w);
    *(float4*)(out + (size_t)node * OUT_FEAT + (gl << 2)) = o;
}

extern "C" void kernel_launch(void* const* d_in, const int* in_sizes, int n_in,
                              void* d_out, int out_size, void* d_ws, size_t ws_size,
                              hipStream_t stream) {
    const float* x  = (const float*)d_in[0];
    const int*   ei = (const int*)d_in[1];     // int64 in reference -> int32 on device
    const float* W  = (const float*)d_in[2];
    const float* a  = (const float*)d_in[3];
    float* out = (float*)d_out;

    // workspace (~53 MB)
    char* p = (char*)d_ws;
    unsigned short* WhB = (unsigned short*)p; p += (size_t)N_NODES * OUT_FEAT * 2; // 12.8 MB
    unsigned short* WTb = (unsigned short*)p; p += (size_t)OUT_FEAT * IN_FEAT * 2; // 16 KB
    float* s_src    = (float*)p;  p += (size_t)N_NODES * 4;
    float* s_tgt    = (float*)p;  p += (size_t)N_NODES * 4;
    unsigned int* segA = (unsigned int*)p; p += (size_t)N_NODES * 4;
    int*   cursorA  = (int*)p;    p += (size_t)N_BKT * N_SUB * 4;
    p = (char*)(((size_t)p + 15) & ~(size_t)15);
    int2*  bucketsA = (int2*)p;   p += (size_t)N_BKT * N_SUB * SUB_CAP * 8;        // 19.2 MB
    int2*  sorted_se = (int2*)p;  p += ((size_t)N_BKT * STAGE_CAP + 1024) * 8;     // 19.2 MB + pad

    init_prep_kernel<<<32, 256, 0, stream>>>(W, cursorA, WTb);
    gemm_mfma_kernel<<<(N_NODES + 63) / 64, 256, 0, stream>>>(x, WTb, a, WhB, s_src, s_tgt);
    scatter_kernel<<<SCAT_BLOCKS, 512, 0, stream>>>(ei, s_src, s_tgt, cursorA, bucketsA);
    sort_bucket_kernel<<<N_BKT, 256, 0, stream>>>(cursorA, bucketsA, sorted_se, segA);
    node_aggr_kernel<<<(N_NODES * 16) / 256, 256, 0, stream>>>(segA, sorted_se, WhB, out);
}

// Round 11
// 128.978 us; speedup vs baseline: 6.6792x; 1.1499x over previous
//
#include <hip/hip_runtime.h>

#define N_NODES 100000
#define N_EDGES 1600000
#define IN_FEAT 128
#define OUT_FEAT 64
#define LRELU_SLOPE 0.2f
#define EPS_DENOM 1e-16f

#define SB_SHIFT 10                     // 1024 nodes per super-bucket
#define NSB 98                          // ceil(100000/1024)
#define N_SUB 8                         // XCD-local sub-regions (scatterA)
#define SUBA_CAP 2432                   // per (SB,sub): mean 2041, +8.6 sigma
#define FB_NODES 128
#define NFB (NSB * 8)                   // 784 fine buckets
#define FB_CAP 2432                     // per fine bucket: mean 2041, +8.7 sigma
#define SFB_CAP (FB_CAP + 128)          // sorted window incl. even-align padding
#define CH 4096                         // edges per scatterA block
#define SCAT_BLOCKS ((N_EDGES + CH - 1) / CH)   // 391

typedef __attribute__((ext_vector_type(8))) short bf16x8;
typedef __attribute__((ext_vector_type(4))) float f32x4;

// ---- float atomic-max via order-preserving uint encoding ----
__device__ __forceinline__ unsigned int enc_f(float x) {
    unsigned int u = __float_as_uint(x);
    return (u & 0x80000000u) ? ~u : (u | 0x80000000u);
}
__device__ __forceinline__ float dec_f(unsigned int u) {
    u = (u & 0x80000000u) ? (u ^ 0x80000000u) : ~u;
    return __uint_as_float(u);
}
#define ENC_NEG_INF 0x007FFFFFu

__device__ __forceinline__ unsigned short f2bf(float f) {   // RNE
    unsigned int u = __float_as_uint(f);
    u = (u + 0x7FFFu + ((u >> 16) & 1u)) >> 16;
    return (unsigned short)u;
}

// init cursorA + convert W -> bf16 transposed WT[n][k]
__global__ __launch_bounds__(256) void init_prep_kernel(
    const float* __restrict__ W, int* __restrict__ cursorA,
    unsigned short* __restrict__ WTb)
{
    const int i = blockIdx.x * 256 + threadIdx.x;
    if (i < NSB * N_SUB) cursorA[i] = i * SUBA_CAP;      // static sub-region starts
    if (i < OUT_FEAT * IN_FEAT) {
        const int n = i >> 7, k = i & 127;
        WTb[i] = f2bf(W[k * OUT_FEAT + n]);
    }
}

// MFMA GEMM: Wh(bf16) = x @ W, fused s_src/s_tgt epilogue (fp32 acc).  [proven]
__global__ __launch_bounds__(256) void gemm_mfma_kernel(
    const float* __restrict__ x, const unsigned short* __restrict__ WTb,
    const float* __restrict__ a, unsigned short* __restrict__ WhB,
    float* __restrict__ s_src, float* __restrict__ s_tgt)
{
    __shared__ __align__(16) unsigned short xs[64][136];
    __shared__ float ssp[4][64], stp[4][64];
    const int tid = threadIdx.x;
    const int wid = tid >> 6, lane = tid & 63;
    const int r0 = blockIdx.x * 64;

    #pragma unroll
    for (int it = 0; it < 8; ++it) {
        const int idx4 = it * 256 + tid;
        const int row = idx4 >> 5;
        const int col = (idx4 & 31) * 4;
        float4 v = make_float4(0.f, 0.f, 0.f, 0.f);
        if (r0 + row < N_NODES) v = *(const float4*)(x + (size_t)(r0 + row) * IN_FEAT + col);
        const unsigned int p0 = (unsigned int)f2bf(v.x) | ((unsigned int)f2bf(v.y) << 16);
        const unsigned int p1 = (unsigned int)f2bf(v.z) | ((unsigned int)f2bf(v.w) << 16);
        *(uint2*)&xs[row][col] = make_uint2(p0, p1);
    }
    __syncthreads();

    const int cgrp = lane >> 4;
    const int cl = lane & 15;
    const int col = wid * 16 + cl;
    f32x4 acc0 = {0.f,0.f,0.f,0.f}, acc1 = acc0, acc2 = acc0, acc3 = acc0;
    #pragma unroll
    for (int kb = 0; kb < IN_FEAT; kb += 32) {
        const bf16x8 bfrag = *(const bf16x8*)(WTb + col * IN_FEAT + kb + cgrp * 8);
        const bf16x8 a0 = *(const bf16x8*)&xs[ 0 + cl][kb + cgrp * 8];
        const bf16x8 a1 = *(const bf16x8*)&xs[16 + cl][kb + cgrp * 8];
        const bf16x8 a2 = *(const bf16x8*)&xs[32 + cl][kb + cgrp * 8];
        const bf16x8 a3 = *(const bf16x8*)&xs[48 + cl][kb + cgrp * 8];
        acc0 = __builtin_amdgcn_mfma_f32_16x16x32_bf16(a0, bfrag, acc0, 0, 0, 0);
        acc1 = __builtin_amdgcn_mfma_f32_16x16x32_bf16(a1, bfrag, acc1, 0, 0, 0);
        acc2 = __builtin_amdgcn_mfma_f32_16x16x32_bf16(a2, bfrag, acc2, 0, 0, 0);
        acc3 = __builtin_amdgcn_mfma_f32_16x16x32_bf16(a3, bfrag, acc3, 0, 0, 0);
    }

    const float a_s = a[col], a_t = a[OUT_FEAT + col];
    #pragma unroll
    for (int mt = 0; mt < 4; ++mt) {
        const f32x4 av = (mt == 0) ? acc0 : (mt == 1) ? acc1 : (mt == 2) ? acc2 : acc3;
        #pragma unroll
        for (int r = 0; r < 4; ++r) {
            const int lrow = mt * 16 + cgrp * 4 + r;
            const float v = av[r];
            const int grow = r0 + lrow;
            if (grow < N_NODES) WhB[(size_t)grow * OUT_FEAT + col] = f2bf(v);
            float ss = v * a_s;
            float st = v * a_t;
            #pragma unroll
            for (int off = 1; off < 16; off <<= 1) {
                ss += __shfl_xor(ss, off, 64);
                st += __shfl_xor(st, off, 64);
            }
            if (cl == 0) { ssp[wid][lrow] = ss; stp[wid][lrow] = st; }
        }
    }
    __syncthreads();
    if (tid < 64 && r0 + tid < N_NODES) {
        s_src[r0 + tid] = (ssp[0][tid] + ssp[1][tid]) + (ssp[2][tid] + ssp[3][tid]);
        s_tgt[r0 + tid] = (stp[0][tid] + stp[1][tid]) + (stp[2][tid] + stp[3][tid]);
    }
}

// Pass A: edge -> 98 coarse super-buckets (runs ~42 edges = 336 B per reservation).
// Packs (src[17b] | tl[10b]<<17, e) where tl = t & 1023.
__global__ __launch_bounds__(512) void scatterA_kernel(
    const int* __restrict__ ei, const float* __restrict__ s_src,
    const float* __restrict__ s_tgt, int* __restrict__ cursorA,
    int2* __restrict__ bucketsA)
{
    __shared__ int hcnt[NSB];
    __shared__ int gbase[NSB];
    __shared__ int lcnt[NSB];
    const int tid = threadIdx.x;
    const int base = blockIdx.x * CH;
    const int sub = blockIdx.x & (N_SUB - 1);   // ~XCD id under round-robin dispatch

    if (tid < NSB) hcnt[tid] = 0;
    __syncthreads();
    #pragma unroll
    for (int k = 0; k < CH / 512; ++k) {
        const int i = base + k * 512 + tid;
        if (i < N_EDGES) atomicAdd(&hcnt[ei[N_EDGES + i] >> SB_SHIFT], 1);
    }
    __syncthreads();
    if (tid < NSB) {
        lcnt[tid] = 0;
        const int c = hcnt[tid];
        gbase[tid] = c ? atomicAdd(&cursorA[tid * N_SUB + sub], c) : 0;
    }
    __syncthreads();
    #pragma unroll
    for (int k = 0; k < CH / 512; ++k) {
        const int i = base + k * 512 + tid;
        if (i < N_EDGES) {
            const int s = ei[i];
            const int t = ei[N_EDGES + i];
            float v = s_src[s] + s_tgt[t];
            v = (v >= 0.0f) ? v : LRELU_SLOPE * v;
            const int sb = t >> SB_SHIFT;
            const int r = atomicAdd(&lcnt[sb], 1);
            bucketsA[gbase[sb] + r] =
                make_int2(s | ((t & 1023) << 17), __float_as_int(v));
        }
    }
}

// Pass B: one block per super-bucket; deposit into per-fine-bucket contiguous
// windows (fine bucket belongs to exactly one SB -> no global atomics).
__global__ __launch_bounds__(1024) void scatterB_kernel(
    const int* __restrict__ cursorA, const int2* __restrict__ bucketsA,
    int* __restrict__ fb_cnt, int2* __restrict__ bucketsB)
{
    __shared__ int cur[8];
    const int sb = blockIdx.x;
    const int tid = threadIdx.x;
    if (tid < 8) cur[tid] = (sb * 8 + tid) * FB_CAP;
    __syncthreads();
    for (int s = 0; s < N_SUB; ++s) {
        const int rbase = (sb * N_SUB + s) * SUBA_CAP;
        const int cnt = cursorA[sb * N_SUB + s] - rbase;
        for (int k = tid; k < cnt; k += 1024) {
            const int2 pk = bucketsA[rbase + k];
            const int fb = (pk.x >> 24) & 7;        // (tl>>7)
            const int pos = atomicAdd(&cur[fb], 1);
            bucketsB[pos] = pk;
        }
    }
    __syncthreads();
    if (tid < 8) fb_cnt[sb * 8 + tid] = cur[tid] - (sb * 8 + tid) * FB_CAP;
}

// One block per fine bucket (128 nodes): stage contiguous edges in LDS,
// per-node count+max, EVEN-ALIGNED scan, deposit (src, w=exp(v-m)),
// emit packed seg[node] = beg<<10 | cnt.
__global__ __launch_bounds__(256) void sort_fine_kernel(
    const int* __restrict__ fb_cnt, const int2* __restrict__ bucketsB,
    int2* __restrict__ sorted_se, unsigned int* __restrict__ segA)
{
    __shared__ int2 stage[FB_CAP];        // 19.5 KB
    __shared__ int cnt[FB_NODES];
    __shared__ int pfx[FB_NODES];
    __shared__ int cur[FB_NODES];
    __shared__ unsigned int m_enc[FB_NODES];
    const int b = blockIdx.x;
    const int tid = threadIdx.x;
    const int tot = fb_cnt[b];

    if (tid < FB_NODES) { cnt[tid] = 0; m_enc[tid] = ENC_NEG_INF; }
    __syncthreads();
    for (int k = tid; k < tot; k += 256) stage[k] = bucketsB[(size_t)b * FB_CAP + k];
    __syncthreads();
    for (int i = tid; i < tot; i += 256) {
        const int2 pk = stage[i];
        const int tl = (pk.x >> 17) & 127;
        atomicAdd(&cnt[tl], 1);
        atomicMax(&m_enc[tl], enc_f(__int_as_float(pk.y)));
    }
    __syncthreads();
    if (tid < FB_NODES) pfx[tid] = (cnt[tid] + 1) & ~1;   // even-padded
    __syncthreads();
    for (int off = 1; off < FB_NODES; off <<= 1) {
        int add = (tid < FB_NODES && tid >= off) ? pfx[tid - off] : 0;
        __syncthreads();
        if (tid < FB_NODES) pfx[tid] += add;
        __syncthreads();
    }
    if (tid < FB_NODES) {
        const int ex = pfx[tid] - ((cnt[tid] + 1) & ~1);  // exclusive, even
        cur[tid] = ex;
        const int node = b * FB_NODES + tid;
        if (node < N_NODES)
            segA[node] = ((unsigned int)(b * SFB_CAP + ex) << 10) | (unsigned int)cnt[tid];
    }
    __syncthreads();
    for (int i = tid; i < tot; i += 256) {
        const int2 pk = stage[i];
        const int tl = (pk.x >> 17) & 127;
        const int pos = atomicAdd(&cur[tl], 1);
        const float w = __expf(__int_as_float(pk.y) - dec_f(m_enc[tl]));
        sorted_se[(size_t)b * SFB_CAP + pos] = make_int2(pk.x & 0x1FFFF, __float_as_int(w));
    }
}

// 4 nodes/wave, 16 lanes/node, 4 features/lane. Exact per-group trip count
// (divergent loop, no wasted gathers); 4-deep unroll = 4 gathers in flight.
__global__ __launch_bounds__(256) void node_aggr_kernel(
    const unsigned int* __restrict__ segA, const int2* __restrict__ sorted_se,
    const unsigned short* __restrict__ WhB, float* __restrict__ out)
{
    const int gtid = blockIdx.x * 256 + threadIdx.x;
    const int node = gtid >> 4;
    const int gl = threadIdx.x & 15;
    const unsigned int sg = segA[node];
    const int beg = (int)(sg >> 10);          // even-aligned
    const int end = beg + (int)(sg & 1023u);

    const char* whb = (const char*)WhB;
    const unsigned int foff = (unsigned int)gl << 3;   // 8 B (4 bf16 feats) per lane
    float a0 = 0.f, a1 = 0.f, a2 = 0.f, a3 = 0.f, sum = 0.f;
    int i = beg;
    for (; i + 4 <= end; i += 4) {
        const int4 q0 = *(const int4*)&sorted_se[i];
        const int4 q1 = *(const int4*)&sorted_se[i + 2];
        const unsigned int s0 = (unsigned int)q0.x & 0x1FFFFu;
        const unsigned int s1 = (unsigned int)q0.z & 0x1FFFFu;
        const unsigned int s2 = (unsigned int)q1.x & 0x1FFFFu;
        const unsigned int s3 = (unsigned int)q1.z & 0x1FFFFu;
        const uint2 g0 = *(const uint2*)(whb + ((s0 << 7) + foff));
        const uint2 g1 = *(const uint2*)(whb + ((s1 << 7) + foff));
        const uint2 g2 = *(const uint2*)(whb + ((s2 << 7) + foff));
        const uint2 g3 = *(const uint2*)(whb + ((s3 << 7) + foff));
        const float w0 = __int_as_float(q0.y), w1 = __int_as_float(q0.w);
        const float w2 = __int_as_float(q1.y), w3 = __int_as_float(q1.w);
        a0 += w0 * __uint_as_float(g0.x << 16) + w1 * __uint_as_float(g1.x << 16)
            + w2 * __uint_as_float(g2.x << 16) + w3 * __uint_as_float(g3.x << 16);
        a1 += w0 * __uint_as_float(g0.x & 0xFFFF0000u) + w1 * __uint_as_float(g1.x & 0xFFFF0000u)
            + w2 * __uint_as_float(g2.x & 0xFFFF0000u) + w3 * __uint_as_float(g3.x & 0xFFFF0000u);
        a2 += w0 * __uint_as_float(g0.y << 16) + w1 * __uint_as_float(g1.y << 16)
            + w2 * __uint_as_float(g2.y << 16) + w3 * __uint_as_float(g3.y << 16);
        a3 += w0 * __uint_as_float(g0.y & 0xFFFF0000u) + w1 * __uint_as_float(g1.y & 0xFFFF0000u)
            + w2 * __uint_as_float(g2.y & 0xFFFF0000u) + w3 * __uint_as_float(g3.y & 0xFFFF0000u);
        sum += (w0 + w1) + (w2 + w3);
    }
    if (i + 2 <= end) {
        const int4 q0 = *(const int4*)&sorted_se[i];
        const unsigned int s0 = (unsigned int)q0.x & 0x1FFFFu;
        const unsigned int s1 = (unsigned int)q0.z & 0x1FFFFu;
        const uint2 g0 = *(const uint2*)(whb + ((s0 << 7) + foff));
        const uint2 g1 = *(const uint2*)(whb + ((s1 << 7) + foff));
        const float w0 = __int_as_float(q0.y), w1 = __int_as_float(q0.w);
        a0 += w0 * __uint_as_float(g0.x << 16) + w1 * __uint_as_float(g1.x << 16);
        a1 += w0 * __uint_as_float(g0.x & 0xFFFF0000u) + w1 * __uint_as_float(g1.x & 0xFFFF0000u);
        a2 += w0 * __uint_as_float(g0.y << 16) + w1 * __uint_as_float(g1.y << 16);
        a3 += w0 * __uint_as_float(g0.y & 0xFFFF0000u) + w1 * __uint_as_float(g1.y & 0xFFFF0000u);
        sum += w0 + w1;
        i += 2;
    }
    if (i < end) {
        const int2 pk = sorted_se[i];
        const unsigned int s0 = (unsigned int)pk.x & 0x1FFFFu;
        const uint2 g0 = *(const uint2*)(whb + ((s0 << 7) + foff));
        const float w0 = __int_as_float(pk.y);
        a0 += w0 * __uint_as_float(g0.x << 16);
        a1 += w0 * __uint_as_float(g0.x & 0xFFFF0000u);
        a2 += w0 * __uint_as_float(g0.y << 16);
        a3 += w0 * __uint_as_float(g0.y & 0xFFFF0000u);
        sum += w0;
    }

    const float inv = 1.0f / (sum + EPS_DENOM);
    float4 o;
    o.x = a0 * inv; o.y = a1 * inv; o.z = a2 * inv; o.w = a3 * inv;
    o.x = (o.x > 0.f) ? o.x : expm1f(o.x);
    o.y = (o.y > 0.f) ? o.y : expm1f(o.y);
    o.z = (o.z > 0.f) ? o.z : expm1f(o.z);
    o.w = (o.w > 0.f) ? o.w : expm1f(o.w);
    *(float4*)(out + (size_t)node * OUT_FEAT + (gl << 2)) = o;
}

extern "C" void kernel_launch(void* const* d_in, const int* in_sizes, int n_in,
                              void* d_out, int out_size, void* d_ws, size_t ws_size,
                              hipStream_t stream) {
    const float* x  = (const float*)d_in[0];
    const int*   ei = (const int*)d_in[1];     // int64 in reference -> int32 on device
    const float* W  = (const float*)d_in[2];
    const float* a  = (const float*)d_in[3];
    float* out = (float*)d_out;

    // workspace (~47 MB)
    char* p = (char*)d_ws;
    unsigned short* WhB = (unsigned short*)p; p += (size_t)N_NODES * OUT_FEAT * 2; // 12.8 MB
    unsigned short* WTb = (unsigned short*)p; p += (size_t)OUT_FEAT * IN_FEAT * 2; // 16 KB
    float* s_src    = (float*)p;  p += (size_t)N_NODES * 4;
    float* s_tgt    = (float*)p;  p += (size_t)N_NODES * 4;
    unsigned int* segA = (unsigned int*)p; p += (size_t)N_NODES * 4;
    int*   cursorA  = (int*)p;    p += (size_t)NSB * N_SUB * 4;
    int*   fb_cnt   = (int*)p;    p += (size_t)NFB * 4;
    p = (char*)(((size_t)p + 15) & ~(size_t)15);
    int2*  bucketsA = (int2*)p;   p += (size_t)NSB * N_SUB * SUBA_CAP * 8;         // 15.3 MB
    int2*  bucketsB = (int2*)p;   p += (size_t)NFB * FB_CAP * 8;                   // 15.3 MB
    int2*  sorted_se = (int2*)p;  p += (size_t)NFB * SFB_CAP * 8;                  // 16.1 MB

    init_prep_kernel<<<32, 256, 0, stream>>>(W, cursorA, WTb);
    gemm_mfma_kernel<<<(N_NODES + 63) / 64, 256, 0, stream>>>(x, WTb, a, WhB, s_src, s_tgt);
    scatterA_kernel<<<SCAT_BLOCKS, 512, 0, stream>>>(ei, s_src, s_tgt, cursorA, bucketsA);
    scatterB_kernel<<<NSB, 1024, 0, stream>>>(cursorA, bucketsA, fb_cnt, bucketsB);
    sort_fine_kernel<<<NFB, 256, 0, stream>>>(fb_cnt, bucketsB, sorted_se, segA);
    node_aggr_kernel<<<(N_NODES * 16) / 256, 256, 0, stream>>>(segA, sorted_se, WhB, out);
}

// Round 12
// 121.005 us; speedup vs baseline: 7.1193x; 1.0659x over previous
//
#include <hip/hip_runtime.h>

#define N_NODES 100000
#define N_EDGES 1600000
#define IN_FEAT 128
#define OUT_FEAT 64
#define LRELU_SLOPE 0.2f
#define EPS_DENOM 1e-16f

#define SB_SHIFT 9                      // 512 nodes per super-bucket
#define SB_NODES 512
#define NSB 196                         // ceil(100000/512)
#define N_SUB 8                         // XCD-local sub-regions (scatterA)
#define SUBA_CAP 1280                   // per (SB,sub): mean ~1028, +8 sigma
#define STAGE_CAP 8960                  // per-SB LDS stage: mean 8192, +8.5 sigma
#define SWIN (STAGE_CAP + SB_NODES)     // sorted window incl. even-align padding
#define CH 4096                         // edges per scatterA block
#define SCAT_BLOCKS ((N_EDGES + CH - 1) / CH)   // 391

typedef __attribute__((ext_vector_type(8))) short bf16x8;
typedef __attribute__((ext_vector_type(4))) float f32x4;

// ---- float atomic-max via order-preserving uint encoding ----
__device__ __forceinline__ unsigned int enc_f(float x) {
    unsigned int u = __float_as_uint(x);
    return (u & 0x80000000u) ? ~u : (u | 0x80000000u);
}
__device__ __forceinline__ float dec_f(unsigned int u) {
    u = (u & 0x80000000u) ? (u ^ 0x80000000u) : ~u;
    return __uint_as_float(u);
}
#define ENC_NEG_INF 0x007FFFFFu

__device__ __forceinline__ unsigned short f2bf(float f) {   // RNE
    unsigned int u = __float_as_uint(f);
    u = (u + 0x7FFFu + ((u >> 16) & 1u)) >> 16;
    return (unsigned short)u;
}

// init cursorA + convert W -> bf16 transposed WT[n][k]
__global__ __launch_bounds__(256) void init_prep_kernel(
    const float* __restrict__ W, int* __restrict__ cursorA,
    unsigned short* __restrict__ WTb)
{
    const int i = blockIdx.x * 256 + threadIdx.x;
    if (i < NSB * N_SUB) cursorA[i] = i * SUBA_CAP;      // static sub-region starts
    if (i < OUT_FEAT * IN_FEAT) {
        const int n = i >> 7, k = i & 127;
        WTb[i] = f2bf(W[k * OUT_FEAT + n]);
    }
}

// MFMA GEMM: Wh(bf16) = x @ W, fused s_src/s_tgt epilogue (fp32 acc).  [proven]
__global__ __launch_bounds__(256) void gemm_mfma_kernel(
    const float* __restrict__ x, const unsigned short* __restrict__ WTb,
    const float* __restrict__ a, unsigned short* __restrict__ WhB,
    float* __restrict__ s_src, float* __restrict__ s_tgt)
{
    __shared__ __align__(16) unsigned short xs[64][136];
    __shared__ float ssp[4][64], stp[4][64];
    const int tid = threadIdx.x;
    const int wid = tid >> 6, lane = tid & 63;
    const int r0 = blockIdx.x * 64;

    #pragma unroll
    for (int it = 0; it < 8; ++it) {
        const int idx4 = it * 256 + tid;
        const int row = idx4 >> 5;
        const int col = (idx4 & 31) * 4;
        float4 v = make_float4(0.f, 0.f, 0.f, 0.f);
        if (r0 + row < N_NODES) v = *(const float4*)(x + (size_t)(r0 + row) * IN_FEAT + col);
        const unsigned int p0 = (unsigned int)f2bf(v.x) | ((unsigned int)f2bf(v.y) << 16);
        const unsigned int p1 = (unsigned int)f2bf(v.z) | ((unsigned int)f2bf(v.w) << 16);
        *(uint2*)&xs[row][col] = make_uint2(p0, p1);
    }
    __syncthreads();

    const int cgrp = lane >> 4;
    const int cl = lane & 15;
    const int col = wid * 16 + cl;
    f32x4 acc0 = {0.f,0.f,0.f,0.f}, acc1 = acc0, acc2 = acc0, acc3 = acc0;
    #pragma unroll
    for (int kb = 0; kb < IN_FEAT; kb += 32) {
        const bf16x8 bfrag = *(const bf16x8*)(WTb + col * IN_FEAT + kb + cgrp * 8);
        const bf16x8 a0 = *(const bf16x8*)&xs[ 0 + cl][kb + cgrp * 8];
        const bf16x8 a1 = *(const bf16x8*)&xs[16 + cl][kb + cgrp * 8];
        const bf16x8 a2 = *(const bf16x8*)&xs[32 + cl][kb + cgrp * 8];
        const bf16x8 a3 = *(const bf16x8*)&xs[48 + cl][kb + cgrp * 8];
        acc0 = __builtin_amdgcn_mfma_f32_16x16x32_bf16(a0, bfrag, acc0, 0, 0, 0);
        acc1 = __builtin_amdgcn_mfma_f32_16x16x32_bf16(a1, bfrag, acc1, 0, 0, 0);
        acc2 = __builtin_amdgcn_mfma_f32_16x16x32_bf16(a2, bfrag, acc2, 0, 0, 0);
        acc3 = __builtin_amdgcn_mfma_f32_16x16x32_bf16(a3, bfrag, acc3, 0, 0, 0);
    }

    const float a_s = a[col], a_t = a[OUT_FEAT + col];
    #pragma unroll
    for (int mt = 0; mt < 4; ++mt) {
        const f32x4 av = (mt == 0) ? acc0 : (mt == 1) ? acc1 : (mt == 2) ? acc2 : acc3;
        #pragma unroll
        for (int r = 0; r < 4; ++r) {
            const int lrow = mt * 16 + cgrp * 4 + r;
            const float v = av[r];
            const int grow = r0 + lrow;
            if (grow < N_NODES) WhB[(size_t)grow * OUT_FEAT + col] = f2bf(v);
            float ss = v * a_s;
            float st = v * a_t;
            #pragma unroll
            for (int off = 1; off < 16; off <<= 1) {
                ss += __shfl_xor(ss, off, 64);
                st += __shfl_xor(st, off, 64);
            }
            if (cl == 0) { ssp[wid][lrow] = ss; stp[wid][lrow] = st; }
        }
    }
    __syncthreads();
    if (tid < 64 && r0 + tid < N_NODES) {
        s_src[r0 + tid] = (ssp[0][tid] + ssp[1][tid]) + (ssp[2][tid] + ssp[3][tid]);
        s_tgt[r0 + tid] = (stp[0][tid] + stp[1][tid]) + (stp[2][tid] + stp[3][tid]);
    }
}

// Pass A: edge -> 196 super-buckets, 1024 threads (24 waves/CU), tgt cached in regs.
// Packs (src[17b] | tl[9b]<<17, e) where tl = t & 511.
__global__ __launch_bounds__(1024) void scatterA_kernel(
    const int* __restrict__ ei, const float* __restrict__ s_src,
    const float* __restrict__ s_tgt, int* __restrict__ cursorA,
    int2* __restrict__ bucketsA)
{
    __shared__ int hcnt[NSB];
    __shared__ int gbase[NSB];
    __shared__ int lcnt[NSB];
    const int tid = threadIdx.x;
    const int base = blockIdx.x * CH;
    const int sub = blockIdx.x & (N_SUB - 1);   // ~XCD id under round-robin dispatch

    if (tid < NSB) hcnt[tid] = 0;
    __syncthreads();
    int tloc[CH / 1024];
    #pragma unroll
    for (int k = 0; k < CH / 1024; ++k) {
        const int i = base + k * 1024 + tid;
        tloc[k] = (i < N_EDGES) ? ei[N_EDGES + i] : -1;
        if (tloc[k] >= 0) atomicAdd(&hcnt[tloc[k] >> SB_SHIFT], 1);
    }
    __syncthreads();
    if (tid < NSB) {
        lcnt[tid] = 0;
        const int c = hcnt[tid];
        gbase[tid] = c ? atomicAdd(&cursorA[tid * N_SUB + sub], c) : 0;
    }
    __syncthreads();
    #pragma unroll
    for (int k = 0; k < CH / 1024; ++k) {
        const int i = base + k * 1024 + tid;
        if (i < N_EDGES) {
            const int s = ei[i];
            const int t = tloc[k];
            float v = s_src[s] + s_tgt[t];
            v = (v >= 0.0f) ? v : LRELU_SLOPE * v;
            const int sb = t >> SB_SHIFT;
            const int r = atomicAdd(&lcnt[sb], 1);
            bucketsA[gbase[sb] + r] =
                make_int2(s | ((t & (SB_NODES - 1)) << 17), __float_as_int(v));
        }
    }
}

// Merged sort: one block per super-bucket (512 nodes, ~8.2K edges in 70KB LDS):
// stage from 8 sub-regions, per-node count+max, even-aligned 512-scan,
// deposit (src, w=exp(v-m)) into the SB's contiguous sorted window,
// emit seg[node] = beg<<10 | cnt.
__global__ __launch_bounds__(512) void sort_sb_kernel(
    const int* __restrict__ cursorA, const int2* __restrict__ bucketsA,
    int2* __restrict__ sorted_se, unsigned int* __restrict__ segA)
{
    __shared__ int2 stage[STAGE_CAP];          // 70 KB
    __shared__ int cnt[SB_NODES];
    __shared__ int pfx[SB_NODES];
    __shared__ int cur[SB_NODES];
    __shared__ unsigned int m_enc[SB_NODES];
    __shared__ int c_ofs[N_SUB + 1];
    const int b = blockIdx.x;
    const int tid = threadIdx.x;

    cnt[tid] = 0;
    m_enc[tid] = ENC_NEG_INF;
    if (tid == 0) {
        int o = 0;
        #pragma unroll
        for (int s = 0; s < N_SUB; ++s) {
            c_ofs[s] = o;
            o += cursorA[b * N_SUB + s] - (b * N_SUB + s) * SUBA_CAP;
        }
        c_ofs[N_SUB] = o;
    }
    __syncthreads();
    const int tot = c_ofs[N_SUB];
    #pragma unroll
    for (int s = 0; s < N_SUB; ++s) {
        const int o = c_ofs[s];
        const int c = c_ofs[s + 1] - o;
        const int2* src = bucketsA + (size_t)(b * N_SUB + s) * SUBA_CAP;
        for (int k = tid; k < c; k += 512) stage[o + k] = src[k];
    }
    __syncthreads();
    for (int i = tid; i < tot; i += 512) {
        const int2 pk = stage[i];
        const int tl = (pk.x >> 17) & (SB_NODES - 1);
        atomicAdd(&cnt[tl], 1);
        atomicMax(&m_enc[tl], enc_f(__int_as_float(pk.y)));
    }
    __syncthreads();
    pfx[tid] = (cnt[tid] + 1) & ~1;            // even-padded
    __syncthreads();
    for (int off = 1; off < SB_NODES; off <<= 1) {
        const int add = (tid >= off) ? pfx[tid - off] : 0;
        __syncthreads();
        pfx[tid] += add;
        __syncthreads();
    }
    {
        const int ex = pfx[tid] - ((cnt[tid] + 1) & ~1);  // exclusive, even
        cur[tid] = ex;
        const int node = b * SB_NODES + tid;
        if (node < N_NODES)
            segA[node] = ((unsigned int)(b * SWIN + ex) << 10) | (unsigned int)cnt[tid];
    }
    __syncthreads();
    for (int i = tid; i < tot; i += 512) {
        const int2 pk = stage[i];
        const int tl = (pk.x >> 17) & (SB_NODES - 1);
        const int pos = atomicAdd(&cur[tl], 1);
        const float w = __expf(__int_as_float(pk.y) - dec_f(m_enc[tl]));
        sorted_se[(size_t)b * SWIN + pos] = make_int2(pk.x & 0x1FFFF, __float_as_int(w));
    }
}

// 4 nodes/wave, 16 lanes/node, 4 features/lane; exact per-group trips,
// 4-deep unroll.  [near-roofline: ~5.7 TB/s delivered]
__global__ __launch_bounds__(256) void node_aggr_kernel(
    const unsigned int* __restrict__ segA, const int2* __restrict__ sorted_se,
    const unsigned short* __restrict__ WhB, float* __restrict__ out)
{
    const int gtid = blockIdx.x * 256 + threadIdx.x;
    const int node = gtid >> 4;
    const int gl = threadIdx.x & 15;
    const unsigned int sg = segA[node];
    const int beg = (int)(sg >> 10);          // even-aligned
    const int end = beg + (int)(sg & 1023u);

    const char* whb = (const char*)WhB;
    const unsigned int foff = (unsigned int)gl << 3;   // 8 B (4 bf16 feats) per lane
    float a0 = 0.f, a1 = 0.f, a2 = 0.f, a3 = 0.f, sum = 0.f;
    int i = beg;
    for (; i + 4 <= end; i += 4) {
        const int4 q0 = *(const int4*)&sorted_se[i];
        const int4 q1 = *(const int4*)&sorted_se[i + 2];
        const unsigned int s0 = (unsigned int)q0.x & 0x1FFFFu;
        const unsigned int s1 = (unsigned int)q0.z & 0x1FFFFu;
        const unsigned int s2 = (unsigned int)q1.x & 0x1FFFFu;
        const unsigned int s3 = (unsigned int)q1.z & 0x1FFFFu;
        const uint2 g0 = *(const uint2*)(whb + ((s0 << 7) + foff));
        const uint2 g1 = *(const uint2*)(whb + ((s1 << 7) + foff));
        const uint2 g2 = *(const uint2*)(whb + ((s2 << 7) + foff));
        const uint2 g3 = *(const uint2*)(whb + ((s3 << 7) + foff));
        const float w0 = __int_as_float(q0.y), w1 = __int_as_float(q0.w);
        const float w2 = __int_as_float(q1.y), w3 = __int_as_float(q1.w);
        a0 += w0 * __uint_as_float(g0.x << 16) + w1 * __uint_as_float(g1.x << 16)
            + w2 * __uint_as_float(g2.x << 16) + w3 * __uint_as_float(g3.x << 16);
        a1 += w0 * __uint_as_float(g0.x & 0xFFFF0000u) + w1 * __uint_as_float(g1.x & 0xFFFF0000u)
            + w2 * __uint_as_float(g2.x & 0xFFFF0000u) + w3 * __uint_as_float(g3.x & 0xFFFF0000u);
        a2 += w0 * __uint_as_float(g0.y << 16) + w1 * __uint_as_float(g1.y << 16)
            + w2 * __uint_as_float(g2.y << 16) + w3 * __uint_as_float(g3.y << 16);
        a3 += w0 * __uint_as_float(g0.y & 0xFFFF0000u) + w1 * __uint_as_float(g1.y & 0xFFFF0000u)
            + w2 * __uint_as_float(g2.y & 0xFFFF0000u) + w3 * __uint_as_float(g3.y & 0xFFFF0000u);
        sum += (w0 + w1) + (w2 + w3);
    }
    if (i + 2 <= end) {
        const int4 q0 = *(const int4*)&sorted_se[i];
        const unsigned int s0 = (unsigned int)q0.x & 0x1FFFFu;
        const unsigned int s1 = (unsigned int)q0.z & 0x1FFFFu;
        const uint2 g0 = *(const uint2*)(whb + ((s0 << 7) + foff));
        const uint2 g1 = *(const uint2*)(whb + ((s1 << 7) + foff));
        const float w0 = __int_as_float(q0.y), w1 = __int_as_float(q0.w);
        a0 += w0 * __uint_as_float(g0.x << 16) + w1 * __uint_as_float(g1.x << 16);
        a1 += w0 * __uint_as_float(g0.x & 0xFFFF0000u) + w1 * __uint_as_float(g1.x & 0xFFFF0000u);
        a2 += w0 * __uint_as_float(g0.y << 16) + w1 * __uint_as_float(g1.y << 16);
        a3 += w0 * __uint_as_float(g0.y & 0xFFFF0000u) + w1 * __uint_as_float(g1.y & 0xFFFF0000u);
        sum += w0 + w1;
        i += 2;
    }
    if (i < end) {
        const int2 pk = sorted_se[i];
        const unsigned int s0 = (unsigned int)pk.x & 0x1FFFFu;
        const uint2 g0 = *(const uint2*)(whb + ((s0 << 7) + foff));
        const float w0 = __int_as_float(pk.y);
        a0 += w0 * __uint_as_float(g0.x << 16);
        a1 += w0 * __uint_as_float(g0.x & 0xFFFF0000u);
        a2 += w0 * __uint_as_float(g0.y << 16);
        a3 += w0 * __uint_as_float(g0.y & 0xFFFF0000u);
        sum += w0;
    }

    const float inv = 1.0f / (sum + EPS_DENOM);
    float4 o;
    o.x = a0 * inv; o.y = a1 * inv; o.z = a2 * inv; o.w = a3 * inv;
    o.x = (o.x > 0.f) ? o.x : expm1f(o.x);
    o.y = (o.y > 0.f) ? o.y : expm1f(o.y);
    o.z = (o.z > 0.f) ? o.z : expm1f(o.z);
    o.w = (o.w > 0.f) ? o.w : expm1f(o.w);
    *(float4*)(out + (size_t)node * OUT_FEAT + (gl << 2)) = o;
}

extern "C" void kernel_launch(void* const* d_in, const int* in_sizes, int n_in,
                              void* d_out, int out_size, void* d_ws, size_t ws_size,
                              hipStream_t stream) {
    const float* x  = (const float*)d_in[0];
    const int*   ei = (const int*)d_in[1];     // int64 in reference -> int32 on device
    const float* W  = (const float*)d_in[2];
    const float* a  = (const float*)d_in[3];
    float* out = (float*)d_out;

    // workspace (~45 MB)
    char* p = (char*)d_ws;
    unsigned short* WhB = (unsigned short*)p; p += (size_t)N_NODES * OUT_FEAT * 2; // 12.8 MB
    unsigned short* WTb = (unsigned short*)p; p += (size_t)OUT_FEAT * IN_FEAT * 2; // 16 KB
    float* s_src    = (float*)p;  p += (size_t)N_NODES * 4;
    float* s_tgt    = (float*)p;  p += (size_t)N_NODES * 4;
    unsigned int* segA = (unsigned int*)p; p += (size_t)N_NODES * 4;
    int*   cursorA  = (int*)p;    p += (size_t)NSB * N_SUB * 4;
    p = (char*)(((size_t)p + 15) & ~(size_t)15);
    int2*  bucketsA = (int2*)p;   p += (size_t)NSB * N_SUB * SUBA_CAP * 8;         // 16.1 MB
    int2*  sorted_se = (int2*)p;  p += (size_t)NSB * SWIN * 8;                     // 14.9 MB

    init_prep_kernel<<<32, 256, 0, stream>>>(W, cursorA, WTb);
    gemm_mfma_kernel<<<(N_NODES + 63) / 64, 256, 0, stream>>>(x, WTb, a, WhB, s_src, s_tgt);
    scatterA_kernel<<<SCAT_BLOCKS, 1024, 0, stream>>>(ei, s_src, s_tgt, cursorA, bucketsA);
    sort_sb_kernel<<<NSB, 512, 0, stream>>>(cursorA, bucketsA, sorted_se, segA);
    node_aggr_kernel<<<(N_NODES * 16) / 256, 256, 0, stream>>>(segA, sorted_se, WhB, out);
}

// Round 13
// 111.100 us; speedup vs baseline: 7.7541x; 1.0892x over previous
//
#include <hip/hip_runtime.h>

#define N_NODES 100000
#define N_EDGES 1600000
#define IN_FEAT 128
#define OUT_FEAT 64
#define LRELU_SLOPE 0.2f
#define EPS_DENOM 1e-16f

#define SB_SHIFT 9                      // 512 nodes per super-bucket
#define SB_NODES 512
#define NSB 196                         // ceil(100000/512)
#define N_SUB 8                         // XCD-local sub-regions (scatterA)
#define SUBA_CAP 1280                   // per (SB,sub): mean ~1028, +8 sigma
#define STAGE_CAP 8960                  // per-SB LDS stage: mean 8192, +8.5 sigma
#define SWIN (STAGE_CAP + SB_NODES)     // sorted window incl. even-align padding
#define CH 4096                         // edges per scatterA block
#define SCAT_BLOCKS ((N_EDGES + CH - 1) / CH)   // 391

typedef __attribute__((ext_vector_type(8))) short bf16x8;
typedef __attribute__((ext_vector_type(4))) float f32x4;

// ---- float atomic-max via order-preserving uint encoding ----
__device__ __forceinline__ unsigned int enc_f(float x) {
    unsigned int u = __float_as_uint(x);
    return (u & 0x80000000u) ? ~u : (u | 0x80000000u);
}
__device__ __forceinline__ float dec_f(unsigned int u) {
    u = (u & 0x80000000u) ? (u ^ 0x80000000u) : ~u;
    return __uint_as_float(u);
}
#define ENC_NEG_INF 0x007FFFFFu

__device__ __forceinline__ unsigned short f2bf(float f) {   // RNE
    unsigned int u = __float_as_uint(f);
    u = (u + 0x7FFFu + ((u >> 16) & 1u)) >> 16;
    return (unsigned short)u;
}

// init cursorA + convert W -> bf16 transposed WT[n][k]
__global__ __launch_bounds__(256) void init_prep_kernel(
    const float* __restrict__ W, int* __restrict__ cursorA,
    unsigned short* __restrict__ WTb)
{
    const int i = blockIdx.x * 256 + threadIdx.x;
    if (i < NSB * N_SUB) cursorA[i] = i * SUBA_CAP;      // static sub-region starts
    if (i < OUT_FEAT * IN_FEAT) {
        const int n = i >> 7, k = i & 127;
        WTb[i] = f2bf(W[k * OUT_FEAT + n]);
    }
}

// MFMA GEMM: Wh(bf16) = x @ W, fused s_src/s_tgt epilogue (fp32 acc).  [proven]
__global__ __launch_bounds__(256) void gemm_mfma_kernel(
    const float* __restrict__ x, const unsigned short* __restrict__ WTb,
    const float* __restrict__ a, unsigned short* __restrict__ WhB,
    float* __restrict__ s_src, float* __restrict__ s_tgt)
{
    __shared__ __align__(16) unsigned short xs[64][136];
    __shared__ float ssp[4][64], stp[4][64];
    const int tid = threadIdx.x;
    const int wid = tid >> 6, lane = tid & 63;
    const int r0 = blockIdx.x * 64;

    #pragma unroll
    for (int it = 0; it < 8; ++it) {
        const int idx4 = it * 256 + tid;
        const int row = idx4 >> 5;
        const int col = (idx4 & 31) * 4;
        float4 v = make_float4(0.f, 0.f, 0.f, 0.f);
        if (r0 + row < N_NODES) v = *(const float4*)(x + (size_t)(r0 + row) * IN_FEAT + col);
        const unsigned int p0 = (unsigned int)f2bf(v.x) | ((unsigned int)f2bf(v.y) << 16);
        const unsigned int p1 = (unsigned int)f2bf(v.z) | ((unsigned int)f2bf(v.w) << 16);
        *(uint2*)&xs[row][col] = make_uint2(p0, p1);
    }
    __syncthreads();

    const int cgrp = lane >> 4;
    const int cl = lane & 15;
    const int col = wid * 16 + cl;
    f32x4 acc0 = {0.f,0.f,0.f,0.f}, acc1 = acc0, acc2 = acc0, acc3 = acc0;
    #pragma unroll
    for (int kb = 0; kb < IN_FEAT; kb += 32) {
        const bf16x8 bfrag = *(const bf16x8*)(WTb + col * IN_FEAT + kb + cgrp * 8);
        const bf16x8 a0 = *(const bf16x8*)&xs[ 0 + cl][kb + cgrp * 8];
        const bf16x8 a1 = *(const bf16x8*)&xs[16 + cl][kb + cgrp * 8];
        const bf16x8 a2 = *(const bf16x8*)&xs[32 + cl][kb + cgrp * 8];
        const bf16x8 a3 = *(const bf16x8*)&xs[48 + cl][kb + cgrp * 8];
        acc0 = __builtin_amdgcn_mfma_f32_16x16x32_bf16(a0, bfrag, acc0, 0, 0, 0);
        acc1 = __builtin_amdgcn_mfma_f32_16x16x32_bf16(a1, bfrag, acc1, 0, 0, 0);
        acc2 = __builtin_amdgcn_mfma_f32_16x16x32_bf16(a2, bfrag, acc2, 0, 0, 0);
        acc3 = __builtin_amdgcn_mfma_f32_16x16x32_bf16(a3, bfrag, acc3, 0, 0, 0);
    }

    const float a_s = a[col], a_t = a[OUT_FEAT + col];
    #pragma unroll
    for (int mt = 0; mt < 4; ++mt) {
        const f32x4 av = (mt == 0) ? acc0 : (mt == 1) ? acc1 : (mt == 2) ? acc2 : acc3;
        #pragma unroll
        for (int r = 0; r < 4; ++r) {
            const int lrow = mt * 16 + cgrp * 4 + r;
            const float v = av[r];
            const int grow = r0 + lrow;
            if (grow < N_NODES) WhB[(size_t)grow * OUT_FEAT + col] = f2bf(v);
            float ss = v * a_s;
            float st = v * a_t;
            #pragma unroll
            for (int off = 1; off < 16; off <<= 1) {
                ss += __shfl_xor(ss, off, 64);
                st += __shfl_xor(st, off, 64);
            }
            if (cl == 0) { ssp[wid][lrow] = ss; stp[wid][lrow] = st; }
        }
    }
    __syncthreads();
    if (tid < 64 && r0 + tid < N_NODES) {
        s_src[r0 + tid] = (ssp[0][tid] + ssp[1][tid]) + (ssp[2][tid] + ssp[3][tid]);
        s_tgt[r0 + tid] = (stp[0][tid] + stp[1][tid]) + (stp[2][tid] + stp[3][tid]);
    }
}

// Pass A: pure streaming binner. Reads only ei, writes 4 B per edge:
// packed = src[17b] | tl[9b]<<17.  No gathers, no score math.
__global__ __launch_bounds__(1024) void scatterA_kernel(
    const int* __restrict__ ei, int* __restrict__ cursorA,
    int* __restrict__ bucketsA)
{
    __shared__ int hcnt[NSB];
    __shared__ int gbase[NSB];
    __shared__ int lcnt[NSB];
    const int tid = threadIdx.x;
    const int base = blockIdx.x * CH;
    const int sub = blockIdx.x & (N_SUB - 1);   // ~XCD id under round-robin dispatch

    if (tid < NSB) hcnt[tid] = 0;
    __syncthreads();
    int tloc[CH / 1024], sloc[CH / 1024];
    #pragma unroll
    for (int k = 0; k < CH / 1024; ++k) {
        const int i = base + k * 1024 + tid;
        tloc[k] = (i < N_EDGES) ? ei[N_EDGES + i] : -1;
        sloc[k] = (i < N_EDGES) ? ei[i] : 0;
        if (tloc[k] >= 0) atomicAdd(&hcnt[tloc[k] >> SB_SHIFT], 1);
    }
    __syncthreads();
    if (tid < NSB) {
        lcnt[tid] = 0;
        const int c = hcnt[tid];
        gbase[tid] = c ? atomicAdd(&cursorA[tid * N_SUB + sub], c) : 0;
    }
    __syncthreads();
    #pragma unroll
    for (int k = 0; k < CH / 1024; ++k) {
        if (tloc[k] >= 0) {
            const int sb = tloc[k] >> SB_SHIFT;
            const int r = atomicAdd(&lcnt[sb], 1);
            bucketsA[gbase[sb] + r] = sloc[k] | ((tloc[k] & (SB_NODES - 1)) << 17);
        }
    }
}

// Merged sort: one block per super-bucket (512 nodes, ~8.2K edges):
// preload s_tgt[SB] to LDS; stage packed edges while gathering s_src[src] (L2),
// computing leaky-relu score + per-node count/max in ONE pass; even-aligned
// 512-scan; deposit (src, w=exp(v-m)); emit seg[node] = beg<<10 | cnt.
__global__ __launch_bounds__(512) void sort_sb_kernel(
    const int* __restrict__ cursorA, const int* __restrict__ bucketsA,
    const float* __restrict__ s_src, const float* __restrict__ s_tgt,
    int2* __restrict__ sorted_se, unsigned int* __restrict__ segA)
{
    __shared__ int2 stage[STAGE_CAP];          // (packed, v)  70 KB
    __shared__ float stgt[SB_NODES];
    __shared__ int cnt[SB_NODES];
    __shared__ int pfx[SB_NODES];
    __shared__ int cur[SB_NODES];
    __shared__ unsigned int m_enc[SB_NODES];
    __shared__ int c_ofs[N_SUB + 1];
    const int b = blockIdx.x;
    const int tid = threadIdx.x;

    cnt[tid] = 0;
    m_enc[tid] = ENC_NEG_INF;
    {
        const int node = b * SB_NODES + tid;
        stgt[tid] = (node < N_NODES) ? s_tgt[node] : 0.0f;
    }
    if (tid == 0) {
        int o = 0;
        #pragma unroll
        for (int s = 0; s < N_SUB; ++s) {
            c_ofs[s] = o;
            o += cursorA[b * N_SUB + s] - (b * N_SUB + s) * SUBA_CAP;
        }
        c_ofs[N_SUB] = o;
    }
    __syncthreads();
    const int tot = c_ofs[N_SUB];
    #pragma unroll
    for (int s = 0; s < N_SUB; ++s) {
        const int o = c_ofs[s];
        const int c = c_ofs[s + 1] - o;
        const int* src = bucketsA + (size_t)(b * N_SUB + s) * SUBA_CAP;
        for (int k = tid; k < c; k += 512) {
            const int pk = src[k];
            const int tl = (pk >> 17) & (SB_NODES - 1);
            float v = s_src[pk & 0x1FFFF] + stgt[tl];
            v = (v >= 0.0f) ? v : LRELU_SLOPE * v;
            stage[o + k] = make_int2(pk, __float_as_int(v));
            atomicAdd(&cnt[tl], 1);
            atomicMax(&m_enc[tl], enc_f(v));
        }
    }
    __syncthreads();
    pfx[tid] = (cnt[tid] + 1) & ~1;            // even-padded
    __syncthreads();
    for (int off = 1; off < SB_NODES; off <<= 1) {
        const int add = (tid >= off) ? pfx[tid - off] : 0;
        __syncthreads();
        pfx[tid] += add;
        __syncthreads();
    }
    {
        const int ex = pfx[tid] - ((cnt[tid] + 1) & ~1);  // exclusive, even
        cur[tid] = ex;
        const int node = b * SB_NODES + tid;
        if (node < N_NODES)
            segA[node] = ((unsigned int)(b * SWIN + ex) << 10) | (unsigned int)cnt[tid];
    }
    __syncthreads();
    for (int i = tid; i < tot; i += 512) {
        const int2 pk = stage[i];
        const int tl = (pk.x >> 17) & (SB_NODES - 1);
        const int pos = atomicAdd(&cur[tl], 1);
        const float w = __expf(__int_as_float(pk.y) - dec_f(m_enc[tl]));
        sorted_se[(size_t)b * SWIN + pos] = make_int2(pk.x & 0x1FFFF, __float_as_int(w));
    }
}

// 4 nodes/wave, 16 lanes/node, 4 features/lane; exact per-group trips,
// 4-deep unroll.  [near-roofline: ~5.7 TB/s delivered]
__global__ __launch_bounds__(256) void node_aggr_kernel(
    const unsigned int* __restrict__ segA, const int2* __restrict__ sorted_se,
    const unsigned short* __restrict__ WhB, float* __restrict__ out)
{
    const int gtid = blockIdx.x * 256 + threadIdx.x;
    const int node = gtid >> 4;
    const int gl = threadIdx.x & 15;
    const unsigned int sg = segA[node];
    const int beg = (int)(sg >> 10);          // even-aligned
    const int end = beg + (int)(sg & 1023u);

    const char* whb = (const char*)WhB;
    const unsigned int foff = (unsigned int)gl << 3;   // 8 B (4 bf16 feats) per lane
    float a0 = 0.f, a1 = 0.f, a2 = 0.f, a3 = 0.f, sum = 0.f;
    int i = beg;
    for (; i + 4 <= end; i += 4) {
        const int4 q0 = *(const int4*)&sorted_se[i];
        const int4 q1 = *(const int4*)&sorted_se[i + 2];
        const unsigned int s0 = (unsigned int)q0.x & 0x1FFFFu;
        const unsigned int s1 = (unsigned int)q0.z & 0x1FFFFu;
        const unsigned int s2 = (unsigned int)q1.x & 0x1FFFFu;
        const unsigned int s3 = (unsigned int)q1.z & 0x1FFFFu;
        const uint2 g0 = *(const uint2*)(whb + ((s0 << 7) + foff));
        const uint2 g1 = *(const uint2*)(whb + ((s1 << 7) + foff));
        const uint2 g2 = *(const uint2*)(whb + ((s2 << 7) + foff));
        const uint2 g3 = *(const uint2*)(whb + ((s3 << 7) + foff));
        const float w0 = __int_as_float(q0.y), w1 = __int_as_float(q0.w);
        const float w2 = __int_as_float(q1.y), w3 = __int_as_float(q1.w);
        a0 += w0 * __uint_as_float(g0.x << 16) + w1 * __uint_as_float(g1.x << 16)
            + w2 * __uint_as_float(g2.x << 16) + w3 * __uint_as_float(g3.x << 16);
        a1 += w0 * __uint_as_float(g0.x & 0xFFFF0000u) + w1 * __uint_as_float(g1.x & 0xFFFF0000u)
            + w2 * __uint_as_float(g2.x & 0xFFFF0000u) + w3 * __uint_as_float(g3.x & 0xFFFF0000u);
        a2 += w0 * __uint_as_float(g0.y << 16) + w1 * __uint_as_float(g1.y << 16)
            + w2 * __uint_as_float(g2.y << 16) + w3 * __uint_as_float(g3.y << 16);
        a3 += w0 * __uint_as_float(g0.y & 0xFFFF0000u) + w1 * __uint_as_float(g1.y & 0xFFFF0000u)
            + w2 * __uint_as_float(g2.y & 0xFFFF0000u) + w3 * __uint_as_float(g3.y & 0xFFFF0000u);
        sum += (w0 + w1) + (w2 + w3);
    }
    if (i + 2 <= end) {
        const int4 q0 = *(const int4*)&sorted_se[i];
        const unsigned int s0 = (unsigned int)q0.x & 0x1FFFFu;
        const unsigned int s1 = (unsigned int)q0.z & 0x1FFFFu;
        const uint2 g0 = *(const uint2*)(whb + ((s0 << 7) + foff));
        const uint2 g1 = *(const uint2*)(whb + ((s1 << 7) + foff));
        const float w0 = __int_as_float(q0.y), w1 = __int_as_float(q0.w);
        a0 += w0 * __uint_as_float(g0.x << 16) + w1 * __uint_as_float(g1.x << 16);
        a1 += w0 * __uint_as_float(g0.x & 0xFFFF0000u) + w1 * __uint_as_float(g1.x & 0xFFFF0000u);
        a2 += w0 * __uint_as_float(g0.y << 16) + w1 * __uint_as_float(g1.y << 16);
        a3 += w0 * __uint_as_float(g0.y & 0xFFFF0000u) + w1 * __uint_as_float(g1.y & 0xFFFF0000u);
        sum += w0 + w1;
        i += 2;
    }
    if (i < end) {
        const int2 pk = sorted_se[i];
        const unsigned int s0 = (unsigned int)pk.x & 0x1FFFFu;
        const uint2 g0 = *(const uint2*)(whb + ((s0 << 7) + foff));
        const float w0 = __int_as_float(pk.y);
        a0 += w0 * __uint_as_float(g0.x << 16);
        a1 += w0 * __uint_as_float(g0.x & 0xFFFF0000u);
        a2 += w0 * __uint_as_float(g0.y << 16);
        a3 += w0 * __uint_as_float(g0.y & 0xFFFF0000u);
        sum += w0;
    }

    const float inv = 1.0f / (sum + EPS_DENOM);
    float4 o;
    o.x = a0 * inv; o.y = a1 * inv; o.z = a2 * inv; o.w = a3 * inv;
    o.x = (o.x > 0.f) ? o.x : expm1f(o.x);
    o.y = (o.y > 0.f) ? o.y : expm1f(o.y);
    o.z = (o.z > 0.f) ? o.z : expm1f(o.z);
    o.w = (o.w > 0.f) ? o.w : expm1f(o.w);
    *(float4*)(out + (size_t)node * OUT_FEAT + (gl << 2)) = o;
}

extern "C" void kernel_launch(void* const* d_in, const int* in_sizes, int n_in,
                              void* d_out, int out_size, void* d_ws, size_t ws_size,
                              hipStream_t stream) {
    const float* x  = (const float*)d_in[0];
    const int*   ei = (const int*)d_in[1];     // int64 in reference -> int32 on device
    const float* W  = (const float*)d_in[2];
    const float* a  = (const float*)d_in[3];
    float* out = (float*)d_out;

    // workspace (~37 MB)
    char* p = (char*)d_ws;
    unsigned short* WhB = (unsigned short*)p; p += (size_t)N_NODES * OUT_FEAT * 2; // 12.8 MB
    unsigned short* WTb = (unsigned short*)p; p += (size_t)OUT_FEAT * IN_FEAT * 2; // 16 KB
    float* s_src    = (float*)p;  p += (size_t)N_NODES * 4;
    float* s_tgt    = (float*)p;  p += (size_t)N_NODES * 4;
    unsigned int* segA = (unsigned int*)p; p += (size_t)N_NODES * 4;
    int*   cursorA  = (int*)p;    p += (size_t)NSB * N_SUB * 4;
    p = (char*)(((size_t)p + 15) & ~(size_t)15);
    int*   bucketsA = (int*)p;    p += (size_t)NSB * N_SUB * SUBA_CAP * 4;         // 8.0 MB
    int2*  sorted_se = (int2*)p;  p += (size_t)NSB * SWIN * 8;                     // 14.9 MB

    init_prep_kernel<<<32, 256, 0, stream>>>(W, cursorA, WTb);
    gemm_mfma_kernel<<<(N_NODES + 63) / 64, 256, 0, stream>>>(x, WTb, a, WhB, s_src, s_tgt);
    scatterA_kernel<<<SCAT_BLOCKS, 1024, 0, stream>>>(ei, cursorA, bucketsA);
    sort_sb_kernel<<<NSB, 512, 0, stream>>>(cursorA, bucketsA, s_src, s_tgt, sorted_se, segA);
    node_aggr_kernel<<<(N_NODES * 16) / 256, 256, 0, stream>>>(segA, sorted_se, WhB, out);
}

// Round 14
// 103.117 us; speedup vs baseline: 8.3544x; 1.0774x over previous
//
#include <hip/hip_runtime.h>

#define N_NODES 100000
#define N_EDGES 1600000
#define IN_FEAT 128
#define OUT_FEAT 64
#define LRELU_SLOPE 0.2f
#define EPS_DENOM 1e-16f

#define SB_SHIFT 8                      // 256 nodes per super-bucket
#define SB_NODES 256
#define NSB 391                         // ceil(100000/256)
#define N_SUB 8                         // XCD-local sub-regions (scatter)
#define SUBA_CAP 704                    // per (SB,sub): mean ~512, +8 sigma
#define STAGE_CAP 4608                  // per-SB LDS stage: mean 4092, +8 sigma
#define SWIN (STAGE_CAP + SB_NODES)     // sorted window incl. even-align padding
#define CH 4096                         // edges per scatter block
#define SCAT_BLOCKS ((N_EDGES + CH - 1) / CH)        // 391
#define GEMM_BLOCKS ((N_NODES + 63) / 64)            // 1563

typedef __attribute__((ext_vector_type(8))) short bf16x8;
typedef __attribute__((ext_vector_type(4))) float f32x4;

// ---- float atomic-max via order-preserving uint encoding ----
__device__ __forceinline__ unsigned int enc_f(float x) {
    unsigned int u = __float_as_uint(x);
    return (u & 0x80000000u) ? ~u : (u | 0x80000000u);
}
__device__ __forceinline__ float dec_f(unsigned int u) {
    u = (u & 0x80000000u) ? (u ^ 0x80000000u) : ~u;
    return __uint_as_float(u);
}
#define ENC_NEG_INF 0x007FFFFFu

__device__ __forceinline__ unsigned short f2bf(float f) {   // RNE
    unsigned int u = __float_as_uint(f);
    u = (u + 0x7FFFu + ((u >> 16) & 1u)) >> 16;
    return (unsigned short)u;
}

// init cursorA + convert W -> bf16 transposed WT[n][k]
__global__ __launch_bounds__(256) void init_prep_kernel(
    const float* __restrict__ W, int* __restrict__ cursorA,
    unsigned short* __restrict__ WTb)
{
    const int i = blockIdx.x * 256 + threadIdx.x;
    if (i < NSB * N_SUB) cursorA[i] = i * SUBA_CAP;      // static sub-region starts
    if (i < OUT_FEAT * IN_FEAT) {
        const int n = i >> 7, k = i & 127;
        WTb[i] = f2bf(W[k * OUT_FEAT + n]);
    }
}

// Heterogeneous fused kernel: blocks [0, SCAT_BLOCKS) run the streaming edge
// binner (memory-bound); blocks [SCAT_BLOCKS, +GEMM_BLOCKS) run the MFMA GEMM
// (compute-bound). Co-resident blocks overlap the two pipes.
__global__ __launch_bounds__(256) void gemm_scatter_kernel(
    const float* __restrict__ x, const unsigned short* __restrict__ WTb,
    const float* __restrict__ a, const int* __restrict__ ei,
    int* __restrict__ cursorA, int* __restrict__ bucketsA,
    unsigned short* __restrict__ WhB,
    float* __restrict__ s_src, float* __restrict__ s_tgt)
{
    __shared__ __align__(16) unsigned short xs[64][136];   // gemm path
    __shared__ float ssp[4][64], stp[4][64];
    __shared__ int hcnt[NSB];                              // scatter path
    __shared__ int gbase[NSB];
    __shared__ int lcnt[NSB];
    const int tid = threadIdx.x;

    if (blockIdx.x < SCAT_BLOCKS) {
        // ---- streaming binner: 4 B per edge, no gathers ----
        const int base = blockIdx.x * CH;
        const int sub = blockIdx.x & (N_SUB - 1);   // ~XCD id under RR dispatch
        for (int j = tid; j < NSB; j += 256) hcnt[j] = 0;
        __syncthreads();
        int tloc[CH / 256], sloc[CH / 256];
        #pragma unroll
        for (int k = 0; k < CH / 256; ++k) {
            const int i = base + k * 256 + tid;
            tloc[k] = (i < N_EDGES) ? ei[N_EDGES + i] : -1;
            sloc[k] = (i < N_EDGES) ? ei[i] : 0;
            if (tloc[k] >= 0) atomicAdd(&hcnt[tloc[k] >> SB_SHIFT], 1);
        }
        __syncthreads();
        for (int j = tid; j < NSB; j += 256) {
            lcnt[j] = 0;
            const int c = hcnt[j];
            gbase[j] = c ? atomicAdd(&cursorA[j * N_SUB + sub], c) : 0;
        }
        __syncthreads();
        #pragma unroll
        for (int k = 0; k < CH / 256; ++k) {
            if (tloc[k] >= 0) {
                const int sb = tloc[k] >> SB_SHIFT;
                const int r = atomicAdd(&lcnt[sb], 1);
                bucketsA[gbase[sb] + r] = sloc[k] | ((tloc[k] & (SB_NODES - 1)) << 17);
            }
        }
        return;
    }

    // ---- MFMA GEMM: Wh(bf16) = x @ W, fused score epilogue ----
    const int wid = tid >> 6, lane = tid & 63;
    const int r0 = (blockIdx.x - SCAT_BLOCKS) * 64;

    #pragma unroll
    for (int it = 0; it < 8; ++it) {
        const int idx4 = it * 256 + tid;
        const int row = idx4 >> 5;
        const int col = (idx4 & 31) * 4;
        float4 v = make_float4(0.f, 0.f, 0.f, 0.f);
        if (r0 + row < N_NODES) v = *(const float4*)(x + (size_t)(r0 + row) * IN_FEAT + col);
        const unsigned int p0 = (unsigned int)f2bf(v.x) | ((unsigned int)f2bf(v.y) << 16);
        const unsigned int p1 = (unsigned int)f2bf(v.z) | ((unsigned int)f2bf(v.w) << 16);
        *(uint2*)&xs[row][col] = make_uint2(p0, p1);
    }
    __syncthreads();

    const int cgrp = lane >> 4;
    const int cl = lane & 15;
    const int col = wid * 16 + cl;
    f32x4 acc0 = {0.f,0.f,0.f,0.f}, acc1 = acc0, acc2 = acc0, acc3 = acc0;
    #pragma unroll
    for (int kb = 0; kb < IN_FEAT; kb += 32) {
        const bf16x8 bfrag = *(const bf16x8*)(WTb + col * IN_FEAT + kb + cgrp * 8);
        const bf16x8 a0 = *(const bf16x8*)&xs[ 0 + cl][kb + cgrp * 8];
        const bf16x8 a1 = *(const bf16x8*)&xs[16 + cl][kb + cgrp * 8];
        const bf16x8 a2 = *(const bf16x8*)&xs[32 + cl][kb + cgrp * 8];
        const bf16x8 a3 = *(const bf16x8*)&xs[48 + cl][kb + cgrp * 8];
        acc0 = __builtin_amdgcn_mfma_f32_16x16x32_bf16(a0, bfrag, acc0, 0, 0, 0);
        acc1 = __builtin_amdgcn_mfma_f32_16x16x32_bf16(a1, bfrag, acc1, 0, 0, 0);
        acc2 = __builtin_amdgcn_mfma_f32_16x16x32_bf16(a2, bfrag, acc2, 0, 0, 0);
        acc3 = __builtin_amdgcn_mfma_f32_16x16x32_bf16(a3, bfrag, acc3, 0, 0, 0);
    }

    const float a_s = a[col], a_t = a[OUT_FEAT + col];
    #pragma unroll
    for (int mt = 0; mt < 4; ++mt) {
        const f32x4 av = (mt == 0) ? acc0 : (mt == 1) ? acc1 : (mt == 2) ? acc2 : acc3;
        #pragma unroll
        for (int r = 0; r < 4; ++r) {
            const int lrow = mt * 16 + cgrp * 4 + r;
            const float v = av[r];
            const int grow = r0 + lrow;
            if (grow < N_NODES) WhB[(size_t)grow * OUT_FEAT + col] = f2bf(v);
            float ss = v * a_s;
            float st = v * a_t;
            #pragma unroll
            for (int off = 1; off < 16; off <<= 1) {
                ss += __shfl_xor(ss, off, 64);
                st += __shfl_xor(st, off, 64);
            }
            if (cl == 0) { ssp[wid][lrow] = ss; stp[wid][lrow] = st; }
        }
    }
    __syncthreads();
    if (tid < 64 && r0 + tid < N_NODES) {
        s_src[r0 + tid] = (ssp[0][tid] + ssp[1][tid]) + (ssp[2][tid] + ssp[3][tid]);
        s_tgt[r0 + tid] = (stp[0][tid] + stp[1][tid]) + (stp[2][tid] + stp[3][tid]);
    }
}

// Merged sort: one block per super-bucket (256 nodes, ~4.1K edges, ~43KB LDS ->
// 3 blocks/CU): preload s_tgt[SB]; stage packed edges while gathering s_src
// (L2) + leaky-relu + per-node count/max in ONE pass; even-aligned scan;
// deposit (src, w=exp(v-m)); emit seg[node] = beg<<10 | cnt.
__global__ __launch_bounds__(512) void sort_sb_kernel(
    const int* __restrict__ cursorA, const int* __restrict__ bucketsA,
    const float* __restrict__ s_src, const float* __restrict__ s_tgt,
    int2* __restrict__ sorted_se, unsigned int* __restrict__ segA)
{
    __shared__ int2 stage[STAGE_CAP];          // (packed, v)  36.9 KB
    __shared__ float stgt[SB_NODES];
    __shared__ int cnt[SB_NODES];
    __shared__ int pfx[SB_NODES];
    __shared__ int cur[SB_NODES];
    __shared__ unsigned int m_enc[SB_NODES];
    __shared__ int c_ofs[N_SUB + 1];
    const int b = blockIdx.x;
    const int tid = threadIdx.x;

    if (tid < SB_NODES) {
        cnt[tid] = 0;
        m_enc[tid] = ENC_NEG_INF;
        const int node = b * SB_NODES + tid;
        stgt[tid] = (node < N_NODES) ? s_tgt[node] : 0.0f;
    }
    if (tid == 0) {
        int o = 0;
        #pragma unroll
        for (int s = 0; s < N_SUB; ++s) {
            c_ofs[s] = o;
            o += cursorA[b * N_SUB + s] - (b * N_SUB + s) * SUBA_CAP;
        }
        c_ofs[N_SUB] = o;
    }
    __syncthreads();
    const int tot = c_ofs[N_SUB];
    #pragma unroll
    for (int s = 0; s < N_SUB; ++s) {
        const int o = c_ofs[s];
        const int c = c_ofs[s + 1] - o;
        const int* src = bucketsA + (size_t)(b * N_SUB + s) * SUBA_CAP;
        for (int k = tid; k < c; k += 512) {
            const int pk = src[k];
            const int tl = (pk >> 17) & (SB_NODES - 1);
            float v = s_src[pk & 0x1FFFF] + stgt[tl];
            v = (v >= 0.0f) ? v : LRELU_SLOPE * v;
            stage[o + k] = make_int2(pk, __float_as_int(v));
            atomicAdd(&cnt[tl], 1);
            atomicMax(&m_enc[tl], enc_f(v));
        }
    }
    __syncthreads();
    if (tid < SB_NODES) pfx[tid] = (cnt[tid] + 1) & ~1;   // even-padded
    __syncthreads();
    for (int off = 1; off < SB_NODES; off <<= 1) {
        const int add = (tid < SB_NODES && tid >= off) ? pfx[tid - off] : 0;
        __syncthreads();
        if (tid < SB_NODES) pfx[tid] += add;
        __syncthreads();
    }
    if (tid < SB_NODES) {
        const int ex = pfx[tid] - ((cnt[tid] + 1) & ~1);  // exclusive, even
        cur[tid] = ex;
        const int node = b * SB_NODES + tid;
        if (node < N_NODES)
            segA[node] = ((unsigned int)(b * SWIN + ex) << 10) | (unsigned int)cnt[tid];
    }
    __syncthreads();
    for (int i = tid; i < tot; i += 512) {
        const int2 pk = stage[i];
        const int tl = (pk.x >> 17) & (SB_NODES - 1);
        const int pos = atomicAdd(&cur[tl], 1);
        const float w = __expf(__int_as_float(pk.y) - dec_f(m_enc[tl]));
        sorted_se[(size_t)b * SWIN + pos] = make_int2(pk.x & 0x1FFFF, __float_as_int(w));
    }
}

// 4 nodes/wave, 16 lanes/node, 4 features/lane; exact per-group trips,
// 4-deep unroll.  [near-roofline: ~5.7 TB/s delivered]
__global__ __launch_bounds__(256) void node_aggr_kernel(
    const unsigned int* __restrict__ segA, const int2* __restrict__ sorted_se,
    const unsigned short* __restrict__ WhB, float* __restrict__ out)
{
    const int gtid = blockIdx.x * 256 + threadIdx.x;
    const int node = gtid >> 4;
    const int gl = threadIdx.x & 15;
    const unsigned int sg = segA[node];
    const int beg = (int)(sg >> 10);          // even-aligned
    const int end = beg + (int)(sg & 1023u);

    const char* whb = (const char*)WhB;
    const unsigned int foff = (unsigned int)gl << 3;   // 8 B (4 bf16 feats) per lane
    float a0 = 0.f, a1 = 0.f, a2 = 0.f, a3 = 0.f, sum = 0.f;
    int i = beg;
    for (; i + 4 <= end; i += 4) {
        const int4 q0 = *(const int4*)&sorted_se[i];
        const int4 q1 = *(const int4*)&sorted_se[i + 2];
        const unsigned int s0 = (unsigned int)q0.x & 0x1FFFFu;
        const unsigned int s1 = (unsigned int)q0.z & 0x1FFFFu;
        const unsigned int s2 = (unsigned int)q1.x & 0x1FFFFu;
        const unsigned int s3 = (unsigned int)q1.z & 0x1FFFFu;
        const uint2 g0 = *(const uint2*)(whb + ((s0 << 7) + foff));
        const uint2 g1 = *(const uint2*)(whb + ((s1 << 7) + foff));
        const uint2 g2 = *(const uint2*)(whb + ((s2 << 7) + foff));
        const uint2 g3 = *(const uint2*)(whb + ((s3 << 7) + foff));
        const float w0 = __int_as_float(q0.y), w1 = __int_as_float(q0.w);
        const float w2 = __int_as_float(q1.y), w3 = __int_as_float(q1.w);
        a0 += w0 * __uint_as_float(g0.x << 16) + w1 * __uint_as_float(g1.x << 16)
            + w2 * __uint_as_float(g2.x << 16) + w3 * __uint_as_float(g3.x << 16);
        a1 += w0 * __uint_as_float(g0.x & 0xFFFF0000u) + w1 * __uint_as_float(g1.x & 0xFFFF0000u)
            + w2 * __uint_as_float(g2.x & 0xFFFF0000u) + w3 * __uint_as_float(g3.x & 0xFFFF0000u);
        a2 += w0 * __uint_as_float(g0.y << 16) + w1 * __uint_as_float(g1.y << 16)
            + w2 * __uint_as_float(g2.y << 16) + w3 * __uint_as_float(g3.y << 16);
        a3 += w0 * __uint_as_float(g0.y & 0xFFFF0000u) + w1 * __uint_as_float(g1.y & 0xFFFF0000u)
            + w2 * __uint_as_float(g2.y & 0xFFFF0000u) + w3 * __uint_as_float(g3.y & 0xFFFF0000u);
        sum += (w0 + w1) + (w2 + w3);
    }
    if (i + 2 <= end) {
        const int4 q0 = *(const int4*)&sorted_se[i];
        const unsigned int s0 = (unsigned int)q0.x & 0x1FFFFu;
        const unsigned int s1 = (unsigned int)q0.z & 0x1FFFFu;
        const uint2 g0 = *(const uint2*)(whb + ((s0 << 7) + foff));
        const uint2 g1 = *(const uint2*)(whb + ((s1 << 7) + foff));
        const float w0 = __int_as_float(q0.y), w1 = __int_as_float(q0.w);
        a0 += w0 * __uint_as_float(g0.x << 16) + w1 * __uint_as_float(g1.x << 16);
        a1 += w0 * __uint_as_float(g0.x & 0xFFFF0000u) + w1 * __uint_as_float(g1.x & 0xFFFF0000u);
        a2 += w0 * __uint_as_float(g0.y << 16) + w1 * __uint_as_float(g1.y << 16);
        a3 += w0 * __uint_as_float(g0.y & 0xFFFF0000u) + w1 * __uint_as_float(g1.y & 0xFFFF0000u);
        sum += w0 + w1;
        i += 2;
    }
    if (i < end) {
        const int2 pk = sorted_se[i];
        const unsigned int s0 = (unsigned int)pk.x & 0x1FFFFu;
        const uint2 g0 = *(const uint2*)(whb + ((s0 << 7) + foff));
        const float w0 = __int_as_float(pk.y);
        a0 += w0 * __uint_as_float(g0.x << 16);
        a1 += w0 * __uint_as_float(g0.x & 0xFFFF0000u);
        a2 += w0 * __uint_as_float(g0.y << 16);
        a3 += w0 * __uint_as_float(g0.y & 0xFFFF0000u);
        sum += w0;
    }

    const float inv = 1.0f / (sum + EPS_DENOM);
    float4 o;
    o.x = a0 * inv; o.y = a1 * inv; o.z = a2 * inv; o.w = a3 * inv;
    o.x = (o.x > 0.f) ? o.x : expm1f(o.x);
    o.y = (o.y > 0.f) ? o.y : expm1f(o.y);
    o.z = (o.z > 0.f) ? o.z : expm1f(o.z);
    o.w = (o.w > 0.f) ? o.w : expm1f(o.w);
    *(float4*)(out + (size_t)node * OUT_FEAT + (gl << 2)) = o;
}

extern "C" void kernel_launch(void* const* d_in, const int* in_sizes, int n_in,
                              void* d_out, int out_size, void* d_ws, size_t ws_size,
                              hipStream_t stream) {
    const float* x  = (const float*)d_in[0];
    const int*   ei = (const int*)d_in[1];     // int64 in reference -> int32 on device
    const float* W  = (const float*)d_in[2];
    const float* a  = (const float*)d_in[3];
    float* out = (float*)d_out;

    // workspace (~39 MB)
    char* p = (char*)d_ws;
    unsigned short* WhB = (unsigned short*)p; p += (size_t)N_NODES * OUT_FEAT * 2; // 12.8 MB
    unsigned short* WTb = (unsigned short*)p; p += (size_t)OUT_FEAT * IN_FEAT * 2; // 16 KB
    float* s_src    = (float*)p;  p += (size_t)N_NODES * 4;
    float* s_tgt    = (float*)p;  p += (size_t)N_NODES * 4;
    unsigned int* segA = (unsigned int*)p; p += (size_t)N_NODES * 4;
    int*   cursorA  = (int*)p;    p += (size_t)NSB * N_SUB * 4;
    p = (char*)(((size_t)p + 15) & ~(size_t)15);
    int*   bucketsA = (int*)p;    p += (size_t)NSB * N_SUB * SUBA_CAP * 4;         // 8.8 MB
    int2*  sorted_se = (int2*)p;  p += (size_t)NSB * SWIN * 8;                     // 15.2 MB

    init_prep_kernel<<<32, 256, 0, stream>>>(W, cursorA, WTb);
    gemm_scatter_kernel<<<SCAT_BLOCKS + GEMM_BLOCKS, 256, 0, stream>>>(
        x, WTb, a, ei, cursorA, bucketsA, WhB, s_src, s_tgt);
    sort_sb_kernel<<<NSB, 512, 0, stream>>>(cursorA, bucketsA, s_src, s_tgt, sorted_se, segA);
    node_aggr_kernel<<<(N_NODES * 16) / 256, 256, 0, stream>>>(segA, sorted_se, WhB, out);
}